// Round 2
// baseline (4085.811 us; speedup 1.0000x reference)
//
#include <hip/hip_runtime.h>

// ---------------------------------------------------------------------------
// StyleGAN2-like generator forward, full pipeline in HIP f32.
// B=8, C=512, output [8,3,32,32].
// ---------------------------------------------------------------------------

#define SQRT2F      1.41421356f
#define MAP_SCALE   4.41941738e-04f   // 0.01/sqrt(512)
#define MOD_SCALE   4.41941738e-02f   // 1/sqrt(512)
#define CONV_SCALE  1.47313913e-02f   // 1/sqrt(512*9)
#define RGB_SCALE   4.41941738e-02f   // 1/sqrt(512)

// ============================ PRNG (JAX threefry) ===========================

__device__ __forceinline__ unsigned rotl32(unsigned x, int r) {
    return (x << r) | (x >> (32 - r));
}

__device__ void threefry2x32(unsigned k0, unsigned k1, unsigned x0, unsigned x1,
                             unsigned& o0, unsigned& o1) {
    unsigned k2 = k0 ^ k1 ^ 0x1BD11BDAu;
    x0 += k0; x1 += k1;
    x0 += x1; x1 = rotl32(x1,13); x1 ^= x0;
    x0 += x1; x1 = rotl32(x1,15); x1 ^= x0;
    x0 += x1; x1 = rotl32(x1,26); x1 ^= x0;
    x0 += x1; x1 = rotl32(x1, 6); x1 ^= x0;
    x0 += k1; x1 += k2 + 1u;
    x0 += x1; x1 = rotl32(x1,17); x1 ^= x0;
    x0 += x1; x1 = rotl32(x1,29); x1 ^= x0;
    x0 += x1; x1 = rotl32(x1,16); x1 ^= x0;
    x0 += x1; x1 = rotl32(x1,24); x1 ^= x0;
    x0 += k2; x1 += k0 + 2u;
    x0 += x1; x1 = rotl32(x1,13); x1 ^= x0;
    x0 += x1; x1 = rotl32(x1,15); x1 ^= x0;
    x0 += x1; x1 = rotl32(x1,26); x1 ^= x0;
    x0 += x1; x1 = rotl32(x1, 6); x1 ^= x0;
    x0 += k0; x1 += k1 + 3u;
    x0 += x1; x1 = rotl32(x1,17); x1 ^= x0;
    x0 += x1; x1 = rotl32(x1,29); x1 ^= x0;
    x0 += x1; x1 = rotl32(x1,16); x1 ^= x0;
    x0 += x1; x1 = rotl32(x1,24); x1 ^= x0;
    x0 += k1; x1 += k2 + 4u;
    x0 += x1; x1 = rotl32(x1,13); x1 ^= x0;
    x0 += x1; x1 = rotl32(x1,15); x1 ^= x0;
    x0 += x1; x1 = rotl32(x1,26); x1 ^= x0;
    x0 += x1; x1 = rotl32(x1, 6); x1 ^= x0;
    x0 += k2; x1 += k0 + 5u;
    o0 = x0; o1 = x1;
}

// bits -> N(0,1) exactly as jax.random.normal (uniform(-1+eps,1) -> sqrt2*erfinv)
__device__ float bits_to_normal(unsigned bits) {
    unsigned m = (bits >> 9) | 0x3F800000u;
    float f = __uint_as_float(m) - 1.0f;
    const float lo = -0.99999994f;  // nextafter(-1,0) in f32
    float u = f * 2.0f + lo;        // (hi-lo) rounds to 2.0f in f32
    u = fmaxf(lo, u);
    // XLA ErfInv f32 (Giles polynomial)
    float w = -log1pf(-u * u);
    float p;
    if (w < 5.0f) {
        w -= 2.5f;
        p = 2.81022636e-08f;
        p = fmaf(p, w, 3.43273939e-07f);
        p = fmaf(p, w, -3.5233877e-06f);
        p = fmaf(p, w, -4.39150654e-06f);
        p = fmaf(p, w, 0.00021858087f);
        p = fmaf(p, w, -0.00125372503f);
        p = fmaf(p, w, -0.00417768164f);
        p = fmaf(p, w, 0.246640727f);
        p = fmaf(p, w, 1.50140941f);
    } else {
        w = sqrtf(w) - 3.0f;
        p = -0.000200214257f;
        p = fmaf(p, w, 0.000100950558f);
        p = fmaf(p, w, 0.00134934322f);
        p = fmaf(p, w, -0.00367342844f);
        p = fmaf(p, w, 0.00573950773f);
        p = fmaf(p, w, -0.0076224613f);
        p = fmaf(p, w, 0.00943887047f);
        p = fmaf(p, w, 1.00167406f);
        p = fmaf(p, w, 2.83297682f);
    }
    return 1.41421354f * (p * u);   // np.sqrt(2) rounded to f32
}

// Counter-mode threefry (jax_threefry_partitionable=True, default since JAX
// 0.4.30): element i of a draw of n<2^32 elements uses counter (hi=0, lo=i)
// and the 32-bit sample is out0 ^ out1. fold_in remains the classic
// threefry_2x32(key, [0, data]).
// noise layers: sizes 128,512,512,2048,2048,8192,8192 (total 21632)
__global__ void noise_kernel(float* __restrict__ nbuf) {
    int g = blockIdx.x * 256 + threadIdx.x;
    if (g >= 21632) return;
    const int off[8] = {0, 128, 640, 1152, 3200, 5248, 13440, 21632};
    int l = 0;
    while (l < 6 && g >= off[l + 1]) l++;
    int i = g - off[l];
    unsigned k0, k1;
    threefry2x32(0u, 7u, 0u, (unsigned)l, k0, k1);      // fold_in(key(7), l)
    unsigned b0, b1;
    threefry2x32(k0, k1, 0u, (unsigned)i, b0, b1);      // counter (0, i)
    nbuf[g] = bits_to_normal(b0 ^ b1);
}

// ============================ small linear kernels ==========================

__global__ void pixelnorm_kernel(const float* __restrict__ z, float* __restrict__ out) {
    int b = blockIdx.x;
    int lane = threadIdx.x;   // 64 threads
    float v[8];
    float s = 0.f;
    #pragma unroll
    for (int j = 0; j < 8; j++) {
        v[j] = z[b * 512 + lane + (j << 6)];
        s += v[j] * v[j];
    }
    #pragma unroll
    for (int off = 32; off > 0; off >>= 1) s += __shfl_xor(s, off, 64);
    float norm = rsqrtf(s * (1.f / 512.f) + 1e-8f);
    #pragma unroll
    for (int j = 0; j < 8; j++)
        out[b * 512 + lane + (j << 6)] = v[j] * norm;
}

// one wave per output element; y[l,b,o] = act(dot(win[b], W[l*512+o]) * wscale + bias*bscale)
__global__ void dot512_kernel(const float* __restrict__ win, const float* __restrict__ W,
                              const float* __restrict__ bias, float* __restrict__ out,
                              int total, float wscale, float bscale, int mode) {
    int gt = blockIdx.x * blockDim.x + threadIdx.x;
    int wv = gt >> 6;
    int lane = gt & 63;
    if (wv >= total) return;
    int l = wv >> 12;
    int r = wv & 4095;
    int b = r >> 9;
    int o = r & 511;
    const float* wrow = W + ((size_t)(l * 512 + o) << 9);
    const float* xrow = win + ((size_t)b << 9);
    float s = 0.f;
    #pragma unroll
    for (int j = 0; j < 8; j++) {
        int k = lane + (j << 6);
        s += wrow[k] * xrow[k];
    }
    #pragma unroll
    for (int off = 32; off > 0; off >>= 1) s += __shfl_xor(s, off, 64);
    if (lane == 0) {
        float v = s * wscale + bias[l * 512 + o] * bscale;
        if (mode) v = (v > 0.f ? v : 0.2f * v) * SQRT2F;
        out[wv] = v;
    }
}

// wsq[l,o,i] = sum_t conv_w[l,o,i,t]^2
__global__ void wsq_kernel(const float* __restrict__ cw, float* __restrict__ wsq) {
    int idx = blockIdx.x * 256 + threadIdx.x;
    if (idx >= 7 * 512 * 512) return;
    const float* p = cw + (size_t)idx * 9;
    float s = 0.f;
    #pragma unroll
    for (int t = 0; t < 9; t++) s += p[t] * p[t];
    wsq[idx] = s;
}

// dem[l,b,o] = rsqrt(scale^2 * sum_i wsq[l,o,i]*s[l,b,i]^2 + 1e-8)
__global__ void demod_kernel(const float* __restrict__ wsq, const float* __restrict__ sc,
                             float* __restrict__ dem, int total) {
    int gt = blockIdx.x * blockDim.x + threadIdx.x;
    int wv = gt >> 6;
    int lane = gt & 63;
    if (wv >= total) return;
    int l = wv >> 12;
    int r = wv & 4095;
    int b = r >> 9;
    int o = r & 511;
    const float* wr = wsq + ((size_t)(l * 512 + o) << 9);
    const float* sr = sc + ((size_t)(l * 8 + b) << 9);
    float s = 0.f;
    #pragma unroll
    for (int j = 0; j < 8; j++) {
        int k = lane + (j << 6);
        float sv = sr[k];
        s += wr[k] * sv * sv;
    }
    #pragma unroll
    for (int off = 32; off > 0; off >>= 1) s += __shfl_xor(s, off, 64);
    if (lane == 0) dem[wv] = rsqrtf(s * (1.f / 4608.f) + 1e-8f);
}

// ================================ conv 3x3 ==================================
// Generic modulated 3x3 conv, pad 1, in-size == out-size == S.
// DILATE: builds zero-stuffed (x2 upsampled) input of HIN -> S=2*HIN+1 in LDS.
// FLIPW: spatially flips weights (transposed conv).
// EPI 0: out = d*scale*conv + ns*noise + bias, lrelu, *sqrt2
// EPI 1: out = d*scale*conv   (blur+noise+lrelu happens in blur_kernel)
template <int S, int HIN, bool DILATE, bool FLIPW, int PXL, int OPT, int CI, int PXT, int EPI>
__global__ __launch_bounds__(256) void conv3x3_kernel(
    const float* __restrict__ x, int in_bstride,
    const float* __restrict__ wgt,       // [512][512][9] for this layer
    const float* __restrict__ sstyle,    // [8][512]
    const float* __restrict__ dem,       // [8][512]
    const float* __restrict__ nbuf,      // noise for this layer (EPI 0) or null
    const float* __restrict__ nstr,      // &noise_strength[l] (EPI 0) or null
    const float* __restrict__ bias,      // conv_bias for layer (EPI 0) or null
    float* __restrict__ out) {
    constexpr int REPS = 256 / PXL;
    constexpr int TO = OPT * REPS;
    constexpr int SP = S + 2;
    constexpr int P2 = S * S;

    __shared__ __align__(16) float slds[CI * SP * SP];
    __shared__ __align__(16) float wlds[CI * 9 * TO];

    const int tid = threadIdx.x;
    const int b = blockIdx.y;
    const int o0 = blockIdx.x * TO;
    const int rep = tid / PXL;
    const int lane_px = tid % PXL;
    const int o_base = o0 + rep * OPT;

    int offj[PXT];
    int pxj[PXT];
    #pragma unroll
    for (int j = 0; j < PXT; j++) {
        int px = lane_px + j * PXL;
        pxj[j] = px;
        if (px >= P2) px = P2 - 1;
        offj[j] = (px / S) * SP + (px % S);   // points at (y, x) in padded frame
    }

    float acc[PXT][OPT];
    #pragma unroll
    for (int j = 0; j < PXT; j++)
        #pragma unroll
        for (int c = 0; c < OPT; c++) acc[j][c] = 0.f;

    for (int idx = tid; idx < CI * SP * SP; idx += 256) slds[idx] = 0.f;

    const float* xb = x + (size_t)b * in_bstride;

    for (int i0 = 0; i0 < 512; i0 += CI) {
        __syncthreads();
        // ---- stage input (scaled by style) ----
        if (!DILATE) {
            for (int i_l = 0; i_l < CI; i_l++) {
                float sv = sstyle[b * 512 + i0 + i_l];
                const float* src = xb + (size_t)(i0 + i_l) * P2;
                for (int px = tid; px < P2; px += 256) {
                    int y = px / S, xx = px % S;
                    slds[i_l * SP * SP + (y + 1) * SP + xx + 1] = src[px] * sv;
                }
            }
        } else {
            for (int i_l = 0; i_l < CI; i_l++) {
                float sv = sstyle[b * 512 + i0 + i_l];
                const float* src = xb + (size_t)(i0 + i_l) * (HIN * HIN);
                for (int px = tid; px < P2; px += 256) {
                    int y = px / S, xx = px % S;
                    float v = 0.f;
                    if ((y & 1) && (xx & 1)) v = src[(y >> 1) * HIN + (xx >> 1)] * sv;
                    slds[i_l * SP * SP + (y + 1) * SP + xx + 1] = v;
                }
            }
        }
        // ---- stage weights: wlds[(i_l*9 + t')*TO + o] ----
        {
            constexpr int W9 = CI * 9;
            for (int idx = tid; idx < TO * W9; idx += 256) {
                int o = idx / W9, r = idx % W9;
                float wv = wgt[(size_t)(o0 + o) * 4608 + (size_t)i0 * 9 + r];
                int i_l = r / 9, t = r % 9;
                int tt = FLIPW ? (8 - t) : t;
                wlds[(i_l * 9 + tt) * TO + o] = wv;
            }
        }
        __syncthreads();
        // ---- compute ----
        for (int i_l = 0; i_l < CI; i_l++) {
            const float* sbase = &slds[i_l * SP * SP];
            #pragma unroll
            for (int t = 0; t < 9; t++) {
                const int toff = (t / 3) * SP + (t % 3);
                float wv[OPT];
                #pragma unroll
                for (int c = 0; c < OPT; c += 4) {
                    float4 w4 = *(const float4*)&wlds[(i_l * 9 + t) * TO + rep * OPT + c];
                    wv[c] = w4.x; wv[c + 1] = w4.y; wv[c + 2] = w4.z; wv[c + 3] = w4.w;
                }
                #pragma unroll
                for (int j = 0; j < PXT; j++) {
                    float v = sbase[offj[j] + toff];
                    #pragma unroll
                    for (int c = 0; c < OPT; c++) acc[j][c] += wv[c] * v;
                }
            }
        }
    }
    // ---- epilogue ----
    float ns = (EPI == 0) ? nstr[0] : 0.f;
    #pragma unroll
    for (int c = 0; c < OPT; c++) {
        int o = o_base + c;
        float dv = dem[b * 512 + o] * CONV_SCALE;
        float bv = (EPI == 0) ? bias[o] : 0.f;
        #pragma unroll
        for (int j = 0; j < PXT; j++) {
            if (pxj[j] < P2) {
                float v = acc[j][c] * dv;
                if (EPI == 0) {
                    v += ns * nbuf[b * P2 + pxj[j]] + bv;
                    v = (v > 0.f ? v : 0.2f * v) * SQRT2F;
                }
                out[((size_t)b * 512 + o) * P2 + pxj[j]] = v;
            }
        }
    }
}

// ============================ blur (4x4 depthwise) ==========================
// input S x S (odd), output (S-1) x (S-1), pad (1,1); epilogue noise+bias+lrelu
template <int S>
__global__ void blur_kernel(const float* __restrict__ xin, const float* __restrict__ nbuf,
                            const float* __restrict__ nstr, const float* __restrict__ bias,
                            float* __restrict__ out) {
    constexpr int O = S - 1;
    int bc = blockIdx.x;                         // b*512 + c
    int px = blockIdx.y * 256 + threadIdx.x;
    if (px >= O * O) return;
    int u = px / O, v = px % O;
    const float* src = xin + (size_t)bc * (S * S);
    const float k1[4] = {0.25f, 0.75f, 0.75f, 0.25f};
    float acc = 0.f;
    #pragma unroll
    for (int a = 0; a < 4; a++) {
        int y = u + a - 1;
        if (y < 0 || y >= S) continue;
        float rsum = 0.f;
        #pragma unroll
        for (int bb = 0; bb < 4; bb++) {
            int xx = v + bb - 1;
            if (xx < 0 || xx >= S) continue;
            rsum += k1[bb] * src[y * S + xx];
        }
        acc += k1[a] * rsum;
    }
    int b = bc >> 9, c = bc & 511;
    float val = acc + nstr[0] * nbuf[b * (O * O) + px] + bias[c];
    val = (val > 0.f ? val : 0.2f * val) * SQRT2F;
    out[(size_t)bc * (O * O) + px] = val;
}

// ======================== skip upsample (up=2, pad 2,1) =====================
template <int H>
__global__ void skipup_kernel(const float* __restrict__ skip, float* __restrict__ out) {
    constexpr int O = 2 * H;
    int idx = blockIdx.x * 256 + threadIdx.x;
    if (idx >= 8 * 3 * O * O) return;
    int px = idx % (O * O);
    int bc = idx / (O * O);
    int u = px / O, v = px % O;
    const float k1[4] = {0.25f, 0.75f, 0.75f, 0.25f};
    const float* src = skip + (size_t)bc * (H * H);
    float acc = 0.f;
    #pragma unroll
    for (int ty = 0; ty < 4; ty++) {
        int r = u + ty - 2;
        if (r < 0 || (r & 1) || (r >> 1) >= H) continue;
        float rsum = 0.f;
        #pragma unroll
        for (int tx = 0; tx < 4; tx++) {
            int cc = v + tx - 2;
            if (cc < 0 || (cc & 1) || (cc >> 1) >= H) continue;
            rsum += k1[tx] * src[(r >> 1) * H + (cc >> 1)];
        }
        acc += k1[ty] * rsum;
    }
    out[(size_t)bc * (O * O) + px] = acc;
}

// ================================ to_rgb ====================================
__global__ void torgb_kernel(const float* __restrict__ x, int P2,
                             const float* __restrict__ rgbw,    // [3][512]
                             const float* __restrict__ srgb,    // [8][512]
                             const float* __restrict__ rbias,   // [3]
                             const float* __restrict__ skipup,  // or null
                             float* __restrict__ dst) {
    int b = blockIdx.x;
    int px = blockIdx.y * 256 + threadIdx.x;
    if (px >= P2) return;
    const float* xb = x + ((size_t)b * 512) * P2 + px;
    const float* sb = srgb + b * 512;
    float a0 = 0.f, a1 = 0.f, a2 = 0.f;
    for (int i = 0; i < 512; i++) {
        float v = xb[(size_t)i * P2];
        float sv = sb[i];
        float vs = v * sv;
        a0 += rgbw[i] * vs;
        a1 += rgbw[512 + i] * vs;
        a2 += rgbw[1024 + i] * vs;
    }
    float o0 = a0 * RGB_SCALE + rbias[0];
    float o1 = a1 * RGB_SCALE + rbias[1];
    float o2 = a2 * RGB_SCALE + rbias[2];
    if (skipup) {
        o0 += skipup[((size_t)b * 3 + 0) * P2 + px];
        o1 += skipup[((size_t)b * 3 + 1) * P2 + px];
        o2 += skipup[((size_t)b * 3 + 2) * P2 + px];
    }
    dst[((size_t)b * 3 + 0) * P2 + px] = o0;
    dst[((size_t)b * 3 + 1) * P2 + px] = o1;
    dst[((size_t)b * 3 + 2) * P2 + px] = o2;
}

// ================================ launch ====================================

extern "C" void kernel_launch(void* const* d_in, const int* in_sizes, int n_in,
                              void* d_out, int out_size, void* d_ws, size_t ws_size,
                              hipStream_t stream) {
    const float* z      = (const float*)d_in[0];
    const float* mlp_w  = (const float*)d_in[1];
    const float* mlp_b  = (const float*)d_in[2];
    const float* cinp   = (const float*)d_in[3];
    const float* conv_w = (const float*)d_in[4];
    const float* cmw    = (const float*)d_in[5];
    const float* cmb    = (const float*)d_in[6];
    const float* cbias  = (const float*)d_in[7];
    const float* nstr   = (const float*)d_in[8];
    const float* rgbw   = (const float*)d_in[9];
    const float* rmw    = (const float*)d_in[10];
    const float* rmb    = (const float*)d_in[11];
    const float* rbias  = (const float*)d_in[12];
    float* out = (float*)d_out;
    float* ws = (float*)d_ws;

    float* wlatA = ws;                  // 4096
    float* wlatB = ws + 4096;           // 4096
    float* sconv = ws + 8192;           // 7*4096
    float* srgb  = ws + 36864;          // 4*4096
    float* dem   = ws + 53248;          // 7*4096
    float* noise = ws + 81920;          // 21632
    float* skipA = ws + 103552;         // 24576
    float* skipB = ws + 128128;         // 24576
    float* skipU = ws + 152704;         // 24576
    float* wsq   = ws + 177280;         // 7*512*512
    float* big0  = ws + 2012288;        // 8*512*1089
    float* big1  = ws + 6472832;        // 8*512*1089

    // mapping network
    pixelnorm_kernel<<<8, 64, 0, stream>>>(z, wlatA);
    float* a = wlatA;
    float* bb = wlatB;
    for (int i = 0; i < 8; i++) {
        dot512_kernel<<<1024, 256, 0, stream>>>(a, mlp_w + (size_t)i * 262144,
                                                mlp_b + i * 512, bb, 4096,
                                                MAP_SCALE, 0.01f, 1);
        float* t = a; a = bb; bb = t;
    }
    // styles
    dot512_kernel<<<7168, 256, 0, stream>>>(a, cmw, cmb, sconv, 7 * 4096, MOD_SCALE, 1.0f, 0);
    dot512_kernel<<<4096, 256, 0, stream>>>(a, rmw, rmb, srgb, 4 * 4096, MOD_SCALE, 1.0f, 0);
    // demod precompute
    wsq_kernel<<<(7 * 512 * 512 + 255) / 256, 256, 0, stream>>>(conv_w, wsq);
    demod_kernel<<<7168, 256, 0, stream>>>(wsq, sconv, dem, 7 * 4096);
    // noise
    noise_kernel<<<(21632 + 255) / 256, 256, 0, stream>>>(noise);

    const size_t LW = 2359296;  // 512*512*9

    // l0: const 4x4 -> big0
    conv3x3_kernel<4, 4, false, false, 16, 4, 8, 1, 0><<<dim3(8, 8), 256, 0, stream>>>(
        cinp, 0, conv_w, sconv, dem, noise, nstr, cbias, big0);
    // to_rgb m0 -> skipA
    torgb_kernel<<<dim3(8, 1), 256, 0, stream>>>(big0, 16, rgbw, srgb, rbias, nullptr, skipA);
    // l1 up: big0(4) -> big1 (9)
    conv3x3_kernel<9, 4, true, true, 128, 8, 8, 1, 1><<<dim3(32, 8), 256, 0, stream>>>(
        big0, 512 * 16, conv_w + LW, sconv + 4096, dem + 4096, nullptr, nullptr, nullptr, big1);
    // blur l1: big1(9) -> big0 (8)
    blur_kernel<9><<<dim3(4096, 1), 256, 0, stream>>>(big1, noise + 128, nstr + 1, cbias + 512, big0);
    // l2: big0(8) -> big1
    conv3x3_kernel<8, 8, false, false, 64, 8, 8, 1, 0><<<dim3(16, 8), 256, 0, stream>>>(
        big0, 512 * 64, conv_w + 2 * LW, sconv + 2 * 4096, dem + 2 * 4096,
        noise + 640, nstr + 2, cbias + 2 * 512, big1);
    // skip 4->8, to_rgb m1
    skipup_kernel<4><<<6, 256, 0, stream>>>(skipA, skipU);
    torgb_kernel<<<dim3(8, 1), 256, 0, stream>>>(big1, 64, rgbw + 1536, srgb + 4096,
                                                 rbias + 3, skipU, skipB);
    // l3 up: big1(8) -> big0 (17)
    conv3x3_kernel<17, 8, true, true, 128, 8, 8, 3, 1><<<dim3(32, 8), 256, 0, stream>>>(
        big1, 512 * 64, conv_w + 3 * LW, sconv + 3 * 4096, dem + 3 * 4096,
        nullptr, nullptr, nullptr, big0);
    // blur l3: big0(17) -> big1 (16)
    blur_kernel<17><<<dim3(4096, 1), 256, 0, stream>>>(big0, noise + 1152, nstr + 3,
                                                       cbias + 3 * 512, big1);
    // l4: big1(16) -> big0
    conv3x3_kernel<16, 16, false, false, 128, 8, 8, 2, 0><<<dim3(32, 8), 256, 0, stream>>>(
        big1, 512 * 256, conv_w + 4 * LW, sconv + 4 * 4096, dem + 4 * 4096,
        noise + 3200, nstr + 4, cbias + 4 * 512, big0);
    // skip 8->16, to_rgb m2
    skipup_kernel<8><<<24, 256, 0, stream>>>(skipB, skipU);
    torgb_kernel<<<dim3(8, 1), 256, 0, stream>>>(big0, 256, rgbw + 2 * 1536, srgb + 2 * 4096,
                                                 rbias + 6, skipU, skipA);
    // l5 up: big0(16) -> big1 (33)
    conv3x3_kernel<33, 16, true, true, 256, 8, 4, 5, 1><<<dim3(64, 8), 256, 0, stream>>>(
        big0, 512 * 256, conv_w + 5 * LW, sconv + 5 * 4096, dem + 5 * 4096,
        nullptr, nullptr, nullptr, big1);
    // blur l5: big1(33) -> big0 (32)
    blur_kernel<33><<<dim3(4096, 4), 256, 0, stream>>>(big1, noise + 5248, nstr + 5,
                                                       cbias + 5 * 512, big0);
    // l6: big0(32) -> big1
    conv3x3_kernel<32, 32, false, false, 256, 8, 4, 4, 0><<<dim3(64, 8), 256, 0, stream>>>(
        big0, 512 * 1024, conv_w + 6 * LW, sconv + 6 * 4096, dem + 6 * 4096,
        noise + 13440, nstr + 6, cbias + 6 * 512, big1);
    // skip 16->32, to_rgb m3 -> out
    skipup_kernel<16><<<96, 256, 0, stream>>>(skipA, skipU);
    torgb_kernel<<<dim3(8, 4), 256, 0, stream>>>(big1, 1024, rgbw + 3 * 1536, srgb + 3 * 4096,
                                                 rbias + 9, skipU, out);
}

// Round 4
// 1641.639 us; speedup vs baseline: 2.4889x; 2.4889x over previous
//
#include <hip/hip_runtime.h>

// ---------------------------------------------------------------------------
// StyleGAN2-like generator forward. Convs via bf16 MFMA implicit GEMM.
// B=8, C=512, output [8,3,32,32] f32.
// ---------------------------------------------------------------------------

#define SQRT2F      1.41421356f
#define MAP_SCALE   4.41941738e-04f   // 0.01/sqrt(512)
#define MOD_SCALE   4.41941738e-02f   // 1/sqrt(512)
#define CONV_SCALE  1.47313913e-02f   // 1/sqrt(512*9)
#define RGB_SCALE   4.41941738e-02f   // 1/sqrt(512)

typedef __attribute__((ext_vector_type(8))) short bf16x8;
typedef __attribute__((ext_vector_type(16))) float f32x16;

__device__ __forceinline__ float bf2f(ushort u) {
    return __uint_as_float(((unsigned)u) << 16);
}
__device__ __forceinline__ ushort f2bf(float f) {
    unsigned u = __float_as_uint(f);
    unsigned r = (u + 0x7FFFu + ((u >> 16) & 1u)) >> 16;
    return (ushort)r;
}

// ============================ PRNG (JAX threefry) ===========================

__device__ __forceinline__ unsigned rotl32(unsigned x, int r) {
    return (x << r) | (x >> (32 - r));
}

__device__ void threefry2x32(unsigned k0, unsigned k1, unsigned x0, unsigned x1,
                             unsigned& o0, unsigned& o1) {
    unsigned k2 = k0 ^ k1 ^ 0x1BD11BDAu;
    x0 += k0; x1 += k1;
    x0 += x1; x1 = rotl32(x1,13); x1 ^= x0;
    x0 += x1; x1 = rotl32(x1,15); x1 ^= x0;
    x0 += x1; x1 = rotl32(x1,26); x1 ^= x0;
    x0 += x1; x1 = rotl32(x1, 6); x1 ^= x0;
    x0 += k1; x1 += k2 + 1u;
    x0 += x1; x1 = rotl32(x1,17); x1 ^= x0;
    x0 += x1; x1 = rotl32(x1,29); x1 ^= x0;
    x0 += x1; x1 = rotl32(x1,16); x1 ^= x0;
    x0 += x1; x1 = rotl32(x1,24); x1 ^= x0;
    x0 += k2; x1 += k0 + 2u;
    x0 += x1; x1 = rotl32(x1,13); x1 ^= x0;
    x0 += x1; x1 = rotl32(x1,15); x1 ^= x0;
    x0 += x1; x1 = rotl32(x1,26); x1 ^= x0;
    x0 += x1; x1 = rotl32(x1, 6); x1 ^= x0;
    x0 += k0; x1 += k1 + 3u;
    x0 += x1; x1 = rotl32(x1,17); x1 ^= x0;
    x0 += x1; x1 = rotl32(x1,29); x1 ^= x0;
    x0 += x1; x1 = rotl32(x1,16); x1 ^= x0;
    x0 += x1; x1 = rotl32(x1,24); x1 ^= x0;
    x0 += k1; x1 += k2 + 4u;
    x0 += x1; x1 = rotl32(x1,13); x1 ^= x0;
    x0 += x1; x1 = rotl32(x1,15); x1 ^= x0;
    x0 += x1; x1 = rotl32(x1,26); x1 ^= x0;
    x0 += x1; x1 = rotl32(x1, 6); x1 ^= x0;
    x0 += k2; x1 += k0 + 5u;
    o0 = x0; o1 = x1;
}

__device__ float bits_to_normal(unsigned bits) {
    unsigned m = (bits >> 9) | 0x3F800000u;
    float f = __uint_as_float(m) - 1.0f;
    const float lo = -0.99999994f;
    float u = f * 2.0f + lo;
    u = fmaxf(lo, u);
    float w = -log1pf(-u * u);
    float p;
    if (w < 5.0f) {
        w -= 2.5f;
        p = 2.81022636e-08f;
        p = fmaf(p, w, 3.43273939e-07f);
        p = fmaf(p, w, -3.5233877e-06f);
        p = fmaf(p, w, -4.39150654e-06f);
        p = fmaf(p, w, 0.00021858087f);
        p = fmaf(p, w, -0.00125372503f);
        p = fmaf(p, w, -0.00417768164f);
        p = fmaf(p, w, 0.246640727f);
        p = fmaf(p, w, 1.50140941f);
    } else {
        w = sqrtf(w) - 3.0f;
        p = -0.000200214257f;
        p = fmaf(p, w, 0.000100950558f);
        p = fmaf(p, w, 0.00134934322f);
        p = fmaf(p, w, -0.00367342844f);
        p = fmaf(p, w, 0.00573950773f);
        p = fmaf(p, w, -0.0076224613f);
        p = fmaf(p, w, 0.00943887047f);
        p = fmaf(p, w, 1.00167406f);
        p = fmaf(p, w, 2.83297682f);
    }
    return 1.41421354f * (p * u);
}

// counter-mode threefry (jax_threefry_partitionable): bits = out0 ^ out1 at ctr (0, i)
__global__ void noise_kernel(float* __restrict__ nbuf) {
    int g = blockIdx.x * 256 + threadIdx.x;
    if (g >= 21632) return;
    const int off[8] = {0, 128, 640, 1152, 3200, 5248, 13440, 21632};
    int l = 0;
    while (l < 6 && g >= off[l + 1]) l++;
    int i = g - off[l];
    unsigned k0, k1;
    threefry2x32(0u, 7u, 0u, (unsigned)l, k0, k1);
    unsigned b0, b1;
    threefry2x32(k0, k1, 0u, (unsigned)i, b0, b1);
    nbuf[g] = bits_to_normal(b0 ^ b1);
}

// ============================ small linear kernels ==========================

__global__ void pixelnorm_kernel(const float* __restrict__ z, float* __restrict__ out) {
    int b = blockIdx.x;
    int lane = threadIdx.x;
    float v[8];
    float s = 0.f;
    #pragma unroll
    for (int j = 0; j < 8; j++) {
        v[j] = z[b * 512 + lane + (j << 6)];
        s += v[j] * v[j];
    }
    #pragma unroll
    for (int off = 32; off > 0; off >>= 1) s += __shfl_xor(s, off, 64);
    float norm = rsqrtf(s * (1.f / 512.f) + 1e-8f);
    #pragma unroll
    for (int j = 0; j < 8; j++)
        out[b * 512 + lane + (j << 6)] = v[j] * norm;
}

__global__ void dot512_kernel(const float* __restrict__ win, const float* __restrict__ W,
                              const float* __restrict__ bias, float* __restrict__ out,
                              int total, float wscale, float bscale, int mode) {
    int gt = blockIdx.x * blockDim.x + threadIdx.x;
    int wv = gt >> 6;
    int lane = gt & 63;
    if (wv >= total) return;
    int l = wv >> 12;
    int r = wv & 4095;
    int b = r >> 9;
    int o = r & 511;
    const float* wrow = W + ((size_t)(l * 512 + o) << 9);
    const float* xrow = win + ((size_t)b << 9);
    float s = 0.f;
    #pragma unroll
    for (int j = 0; j < 8; j++) {
        int k = lane + (j << 6);
        s += wrow[k] * xrow[k];
    }
    #pragma unroll
    for (int off = 32; off > 0; off >>= 1) s += __shfl_xor(s, off, 64);
    if (lane == 0) {
        float v = s * wscale + bias[l * 512 + o] * bscale;
        if (mode) v = (v > 0.f ? v : 0.2f * v) * SQRT2F;
        out[wv] = v;
    }
}

// Repack weights for one layer: Wb[t][o][i] (bf16, tap flipped if flip) and
// wsq[o*512+i] = sum_t w^2 (f32) fused.
__global__ void wbconv_kernel(const float* __restrict__ cw, int l, int flip,
                              ushort* __restrict__ wb, float* __restrict__ wsq) {
    int idx = blockIdx.x * 256 + threadIdx.x;   // o*512 + i
    if (idx >= 512 * 512) return;
    int o = idx >> 9, i = idx & 511;
    const float* p = cw + (((size_t)l * 262144) + idx) * 9;
    float w9[9];
    float s = 0.f;
    #pragma unroll
    for (int t = 0; t < 9; t++) { w9[t] = p[t]; s += w9[t] * w9[t]; }
    wsq[idx] = s;
    #pragma unroll
    for (int t = 0; t < 9; t++) {
        int tsrc = flip ? (8 - t) : t;
        wb[((size_t)(t * 512 + o) << 9) + i] = f2bf(w9[tsrc]);
    }
}

// demod for one layer: dm[b*512+o] = rsqrt(sum_i wsq[o,i]*s[b,i]^2 /4608 + 1e-8)
__global__ void demod_kernel(const float* __restrict__ wsq, const float* __restrict__ sc,
                             float* __restrict__ dm) {
    int gt = blockIdx.x * blockDim.x + threadIdx.x;
    int wv = gt >> 6;           // 0..4095
    int lane = gt & 63;
    if (wv >= 4096) return;
    int b = wv >> 9;
    int o = wv & 511;
    const float* wr = wsq + ((size_t)o << 9);
    const float* sr = sc + ((size_t)b << 9);
    float s = 0.f;
    #pragma unroll
    for (int j = 0; j < 8; j++) {
        int k = lane + (j << 6);
        float sv = sr[k];
        s += wr[k] * sv * sv;
    }
    #pragma unroll
    for (int off = 32; off > 0; off >>= 1) s += __shfl_xor(s, off, 64);
    if (lane == 0) dm[wv] = rsqrtf(s * (1.f / 4608.f) + 1e-8f);
}

// ========================== MFMA implicit-GEMM conv =========================
// out[b][o][px] = sum_{i,t} W[o][i][t] * xpad_scaled[b][i][px + off_t]
// Block: 256 thr = 4 waves. Block tile: m=256 (o), n=32 (linear px).
// Wave w: o-range [bx*256 + w*64, +64) as two 32-row MFMA sub-tiles.
// B staged in LDS as [pixel][channel] bf16 (CIP=40 pad), CI=32 chans/chunk.
// DILATE: builds zero-stuffed 2x-upsampled input directly in LDS.
// EPI 0: v=acc*dem*scale + ns*noise + bias, lrelu*sqrt2 ; EPI 1: v=acc*dem*scale
template <int S, int HIN, bool DILATE, bool IN_BF16, int ROWS, int EPI>
__global__ __launch_bounds__(256) void mfma_conv(
    const void* __restrict__ xin, int in_bstride,     // per-batch elements
    const ushort* __restrict__ wb,                    // [9][512][512] bf16
    const float* __restrict__ sstyle,                 // [8][512]
    const float* __restrict__ dem,                    // [8][512]
    const float* __restrict__ nbuf, const float* __restrict__ nstr,
    const float* __restrict__ bias,
    ushort* __restrict__ outp)                        // [8][512][S*S] bf16
{
    constexpr int P2 = S * S, SP = S + 2, CI = 32, CIP = 40;
    constexpr int LDSPX = ROWS * SP;
    __shared__ __align__(16) ushort bstage[LDSPX * CIP];

    const int tid = threadIdx.x;
    const int lane = tid & 63;
    const int wv = tid >> 6;
    const int b = blockIdx.z;
    const int o0 = blockIdx.x * 256 + wv * 64;
    const int n0 = blockIdx.y * 32;
    const int Y0 = n0 / S;
    const int hf = lane >> 5;
    const int l31 = lane & 31;

    int px = n0 + l31;
    bool valid = px < P2;
    int pxc = valid ? px : (P2 - 1);
    int py = pxc / S, pxx = pxc % S;
    const int pixbase = ((py - Y0) * SP + pxx) * CIP;

    f32x16 acc0 = (f32x16)0.0f;
    f32x16 acc1 = (f32x16)0.0f;

    const float* sb = sstyle + b * 512;
    const size_t boff = (size_t)b * in_bstride;

    for (int i0 = 0; i0 < 512; i0 += CI) {
        __syncthreads();
        // ---- stage CI channels, region rows [Y0, Y0+ROWS) padded, full width ----
        for (int idx = tid; idx < CI * LDSPX; idx += 256) {
            int i_l = idx / LDSPX;
            int pr = idx % LDSPX;
            int rl = pr / SP, cc = pr % SP;
            float v = 0.f;
            if (!DILATE) {
                int iy = Y0 + rl - 1, ix = cc - 1;
                if (iy >= 0 && iy < S && ix >= 0 && ix < S) {
                    size_t a = boff + (size_t)(i0 + i_l) * P2 + iy * S + ix;
                    v = IN_BF16 ? bf2f(((const ushort*)xin)[a]) : ((const float*)xin)[a];
                }
            } else {
                int yd = Y0 + rl - 1, xd = cc - 1;
                if (yd >= 0 && yd < S && xd >= 0 && xd < S && (yd & 1) && (xd & 1)) {
                    size_t a = boff + (size_t)(i0 + i_l) * (HIN * HIN) + (yd >> 1) * HIN + (xd >> 1);
                    v = bf2f(((const ushort*)xin)[a]);
                }
            }
            v *= sb[i0 + i_l];
            bstage[pr * CIP + i_l] = f2bf(v);
        }
        __syncthreads();
        // ---- compute: 9 taps x 2 k-steps, 2 m-sub-tiles ----
        const ushort* wb0 = wb + i0;
        #pragma unroll
        for (int t = 0; t < 9; t++) {
            const int toff = ((t / 3) * SP + (t % 3)) * CIP;
            #pragma unroll
            for (int s = 0; s < 2; s++) {
                const int kl = s * 16 + hf * 8;
                bf16x8 bf = *(const bf16x8*)&bstage[pixbase + toff + kl];
                const ushort* wp = wb0 + ((size_t)(t * 512 + o0 + l31) << 9) + kl;
                bf16x8 a0 = *(const bf16x8*)wp;
                bf16x8 a1 = *(const bf16x8*)(wp + (32 << 9));
                acc0 = __builtin_amdgcn_mfma_f32_32x32x16_bf16(a0, bf, acc0, 0, 0, 0);
                acc1 = __builtin_amdgcn_mfma_f32_32x32x16_bf16(a1, bf, acc1, 0, 0, 0);
            }
        }
    }
    // ---- epilogue ----
    float ns = 0.f, noisev = 0.f;
    if (EPI == 0) {
        ns = nstr[0];
        if (valid) noisev = nbuf[b * P2 + px];
    }
    if (!valid) return;
    #pragma unroll
    for (int sub = 0; sub < 2; sub++) {
        #pragma unroll
        for (int r = 0; r < 16; r++) {
            float av = (sub == 0) ? acc0[r] : acc1[r];
            int m = (r & 3) + 8 * (r >> 2) + 4 * hf;
            int o = o0 + sub * 32 + m;
            float v = av * dem[b * 512 + o] * CONV_SCALE;
            if (EPI == 0) {
                v += ns * noisev + bias[o];
                v = (v > 0.f ? v : 0.2f * v) * SQRT2F;
            }
            outp[((size_t)b * 512 + o) * P2 + px] = f2bf(v);
        }
    }
}

// ============================ blur (4x4 depthwise) ==========================
template <int S>
__global__ void blur_kernel(const ushort* __restrict__ xin, const float* __restrict__ nbuf,
                            const float* __restrict__ nstr, const float* __restrict__ bias,
                            ushort* __restrict__ out) {
    constexpr int O = S - 1;
    int bc = blockIdx.x;
    int px = blockIdx.y * 256 + threadIdx.x;
    if (px >= O * O) return;
    int u = px / O, v = px % O;
    const ushort* src = xin + (size_t)bc * (S * S);
    const float k1[4] = {0.25f, 0.75f, 0.75f, 0.25f};
    float acc = 0.f;
    #pragma unroll
    for (int a = 0; a < 4; a++) {
        int y = u + a - 1;
        if (y < 0 || y >= S) continue;
        float rsum = 0.f;
        #pragma unroll
        for (int bb = 0; bb < 4; bb++) {
            int xx = v + bb - 1;
            if (xx < 0 || xx >= S) continue;
            rsum += k1[bb] * bf2f(src[y * S + xx]);
        }
        acc += k1[a] * rsum;
    }
    int b = bc >> 9, c = bc & 511;
    float val = acc + nstr[0] * nbuf[b * (O * O) + px] + bias[c];
    val = (val > 0.f ? val : 0.2f * val) * SQRT2F;
    out[(size_t)bc * (O * O) + px] = f2bf(val);
}

// ======================== skip upsample (up=2, pad 2,1) =====================
template <int H>
__global__ void skipup_kernel(const float* __restrict__ skip, float* __restrict__ out) {
    constexpr int O = 2 * H;
    int idx = blockIdx.x * 256 + threadIdx.x;
    if (idx >= 8 * 3 * O * O) return;
    int px = idx % (O * O);
    int bc = idx / (O * O);
    int u = px / O, v = px % O;
    const float k1[4] = {0.25f, 0.75f, 0.75f, 0.25f};
    const float* src = skip + (size_t)bc * (H * H);
    float acc = 0.f;
    #pragma unroll
    for (int ty = 0; ty < 4; ty++) {
        int r = u + ty - 2;
        if (r < 0 || (r & 1) || (r >> 1) >= H) continue;
        float rsum = 0.f;
        #pragma unroll
        for (int tx = 0; tx < 4; tx++) {
            int cc = v + tx - 2;
            if (cc < 0 || (cc & 1) || (cc >> 1) >= H) continue;
            rsum += k1[tx] * src[(r >> 1) * H + (cc >> 1)];
        }
        acc += k1[ty] * rsum;
    }
    out[(size_t)bc * (O * O) + px] = acc;
}

// ================================ to_rgb ====================================
__global__ void torgb_kernel(const ushort* __restrict__ x, int P2,
                             const float* __restrict__ rgbw,
                             const float* __restrict__ srgb,
                             const float* __restrict__ rbias,
                             const float* __restrict__ skipup,
                             float* __restrict__ dst) {
    int b = blockIdx.x;
    int px = blockIdx.y * 256 + threadIdx.x;
    if (px >= P2) return;
    const ushort* xb = x + ((size_t)b * 512) * P2 + px;
    const float* sb = srgb + b * 512;
    float a0 = 0.f, a1 = 0.f, a2 = 0.f;
    for (int i = 0; i < 512; i++) {
        float v = bf2f(xb[(size_t)i * P2]);
        float vs = v * sb[i];
        a0 += rgbw[i] * vs;
        a1 += rgbw[512 + i] * vs;
        a2 += rgbw[1024 + i] * vs;
    }
    float o0 = a0 * RGB_SCALE + rbias[0];
    float o1 = a1 * RGB_SCALE + rbias[1];
    float o2 = a2 * RGB_SCALE + rbias[2];
    if (skipup) {
        o0 += skipup[((size_t)b * 3 + 0) * P2 + px];
        o1 += skipup[((size_t)b * 3 + 1) * P2 + px];
        o2 += skipup[((size_t)b * 3 + 2) * P2 + px];
    }
    dst[((size_t)b * 3 + 0) * P2 + px] = o0;
    dst[((size_t)b * 3 + 1) * P2 + px] = o1;
    dst[((size_t)b * 3 + 2) * P2 + px] = o2;
}

// ================================ launch ====================================

extern "C" void kernel_launch(void* const* d_in, const int* in_sizes, int n_in,
                              void* d_out, int out_size, void* d_ws, size_t ws_size,
                              hipStream_t stream) {
    const float* z      = (const float*)d_in[0];
    const float* mlp_w  = (const float*)d_in[1];
    const float* mlp_b  = (const float*)d_in[2];
    const float* cinp   = (const float*)d_in[3];
    const float* conv_w = (const float*)d_in[4];
    const float* cmw    = (const float*)d_in[5];
    const float* cmb    = (const float*)d_in[6];
    const float* cbias  = (const float*)d_in[7];
    const float* nstr   = (const float*)d_in[8];
    const float* rgbw   = (const float*)d_in[9];
    const float* rmw    = (const float*)d_in[10];
    const float* rmb    = (const float*)d_in[11];
    const float* rbias  = (const float*)d_in[12];
    float* out = (float*)d_out;
    float* ws = (float*)d_ws;

    // ---- workspace layout (float-slot offsets; sizes in f-slots) ----
    float* wlatA = ws;                       // 4096
    float* wlatB = ws + 4096;                // 4096
    float* sconv = ws + 8192;                // 7*4096 = 28672
    float* srgb  = ws + 36864;               // 4*4096 = 16384
    float* dem   = ws + 53248;               // 7*4096 = 28672
    float* noise = ws + 81920;               // 21632
    float* skipA = ws + 103552;              // 24576
    float* skipB = ws + 128128;              // 24576
    float* skipU = ws + 152704;              // 24576
    float* wsq   = ws + 177280;              // 512*512 = 262144 -> ends 439424
    ushort* wbuf = (ushort*)(ws + 439424);   // 9*512*512 bf16 = 1179648 f-slots -> ends 1619072
    ushort* bigA = (ushort*)(ws + 1619072);  // 8*512*1089 bf16 = 2230272 f-slots -> ends 3849344
    ushort* bigB = (ushort*)(ws + 3849344);  // same -> ends 6079616

    // mapping network
    pixelnorm_kernel<<<8, 64, 0, stream>>>(z, wlatA);
    float* a = wlatA;
    float* bb = wlatB;
    for (int i = 0; i < 8; i++) {
        dot512_kernel<<<1024, 256, 0, stream>>>(a, mlp_w + (size_t)i * 262144,
                                                mlp_b + i * 512, bb, 4096,
                                                MAP_SCALE, 0.01f, 1);
        float* t = a; a = bb; bb = t;
    }
    // styles
    dot512_kernel<<<7168, 256, 0, stream>>>(a, cmw, cmb, sconv, 7 * 4096, MOD_SCALE, 1.0f, 0);
    dot512_kernel<<<4096, 256, 0, stream>>>(a, rmw, rmb, srgb, 4 * 4096, MOD_SCALE, 1.0f, 0);
    // noise
    noise_kernel<<<(21632 + 255) / 256, 256, 0, stream>>>(noise);

    // ---------------- layer 0 (4x4, EPI0) -> bigA ----------------
    wbconv_kernel<<<1024, 256, 0, stream>>>(conv_w, 0, 0, wbuf, wsq);
    demod_kernel<<<1024, 256, 0, stream>>>(wsq, sconv, dem);
    mfma_conv<4, 4, false, false, 6, 0><<<dim3(2, 1, 8), 256, 0, stream>>>(
        cinp, 0, wbuf, sconv, dem, noise, nstr, cbias, bigA);
    torgb_kernel<<<dim3(8, 1), 256, 0, stream>>>(bigA, 16, rgbw, srgb, rbias, nullptr, skipA);

    // ---------------- layer 1 (up 4->9, EPI1) -> bigB, blur -> bigA ----------------
    wbconv_kernel<<<1024, 256, 0, stream>>>(conv_w, 1, 1, wbuf, wsq);
    demod_kernel<<<1024, 256, 0, stream>>>(wsq, sconv + 4096, dem + 4096);
    mfma_conv<9, 4, true, true, 7, 1><<<dim3(2, 3, 8), 256, 0, stream>>>(
        bigA, 512 * 16, wbuf, sconv + 4096, dem + 4096, nullptr, nullptr, nullptr, bigB);
    blur_kernel<9><<<dim3(4096, 1), 256, 0, stream>>>(bigB, noise + 128, nstr + 1,
                                                      cbias + 512, bigA);

    // ---------------- layer 2 (8x8, EPI0) -> bigB ----------------
    wbconv_kernel<<<1024, 256, 0, stream>>>(conv_w, 2, 0, wbuf, wsq);
    demod_kernel<<<1024, 256, 0, stream>>>(wsq, sconv + 2 * 4096, dem + 2 * 4096);
    mfma_conv<8, 8, false, true, 6, 0><<<dim3(2, 2, 8), 256, 0, stream>>>(
        bigA, 512 * 64, wbuf, sconv + 2 * 4096, dem + 2 * 4096,
        noise + 640, nstr + 2, cbias + 2 * 512, bigB);
    skipup_kernel<4><<<6, 256, 0, stream>>>(skipA, skipU);
    torgb_kernel<<<dim3(8, 1), 256, 0, stream>>>(bigB, 64, rgbw + 1536, srgb + 4096,
                                                 rbias + 3, skipU, skipB);

    // ---------------- layer 3 (up 8->17, EPI1) -> bigA, blur -> bigB ----------------
    wbconv_kernel<<<1024, 256, 0, stream>>>(conv_w, 3, 1, wbuf, wsq);
    demod_kernel<<<1024, 256, 0, stream>>>(wsq, sconv + 3 * 4096, dem + 3 * 4096);
    mfma_conv<17, 8, true, true, 5, 1><<<dim3(2, 10, 8), 256, 0, stream>>>(
        bigB, 512 * 64, wbuf, sconv + 3 * 4096, dem + 3 * 4096, nullptr, nullptr, nullptr, bigA);
    blur_kernel<17><<<dim3(4096, 1), 256, 0, stream>>>(bigA, noise + 1152, nstr + 3,
                                                       cbias + 3 * 512, bigB);

    // ---------------- layer 4 (16x16, EPI0) -> bigA ----------------
    wbconv_kernel<<<1024, 256, 0, stream>>>(conv_w, 4, 0, wbuf, wsq);
    demod_kernel<<<1024, 256, 0, stream>>>(wsq, sconv + 4 * 4096, dem + 4 * 4096);
    mfma_conv<16, 16, false, true, 4, 0><<<dim3(2, 8, 8), 256, 0, stream>>>(
        bigB, 512 * 256, wbuf, sconv + 4 * 4096, dem + 4 * 4096,
        noise + 3200, nstr + 4, cbias + 4 * 512, bigA);
    skipup_kernel<8><<<24, 256, 0, stream>>>(skipB, skipU);
    torgb_kernel<<<dim3(8, 1), 256, 0, stream>>>(bigA, 256, rgbw + 2 * 1536, srgb + 2 * 4096,
                                                 rbias + 6, skipU, skipA);

    // ---------------- layer 5 (up 16->33, EPI1) -> bigB, blur -> bigA ----------------
    wbconv_kernel<<<1024, 256, 0, stream>>>(conv_w, 5, 1, wbuf, wsq);
    demod_kernel<<<1024, 256, 0, stream>>>(wsq, sconv + 5 * 4096, dem + 5 * 4096);
    mfma_conv<33, 16, true, true, 4, 1><<<dim3(2, 35, 8), 256, 0, stream>>>(
        bigA, 512 * 256, wbuf, sconv + 5 * 4096, dem + 5 * 4096, nullptr, nullptr, nullptr, bigB);
    blur_kernel<33><<<dim3(4096, 4), 256, 0, stream>>>(bigB, noise + 5248, nstr + 5,
                                                       cbias + 5 * 512, bigA);

    // ---------------- layer 6 (32x32, EPI0) -> bigB ----------------
    wbconv_kernel<<<1024, 256, 0, stream>>>(conv_w, 6, 0, wbuf, wsq);
    demod_kernel<<<1024, 256, 0, stream>>>(wsq, sconv + 6 * 4096, dem + 6 * 4096);
    mfma_conv<32, 32, false, true, 3, 0><<<dim3(2, 32, 8), 256, 0, stream>>>(
        bigA, 512 * 1024, wbuf, sconv + 6 * 4096, dem + 6 * 4096,
        noise + 13440, nstr + 6, cbias + 6 * 512, bigB);
    skipup_kernel<16><<<96, 256, 0, stream>>>(skipA, skipU);
    torgb_kernel<<<dim3(8, 4), 256, 0, stream>>>(bigB, 1024, rgbw + 3 * 1536, srgb + 3 * 4096,
                                                 rbias + 9, skipU, out);
}

// Round 5
// 1146.542 us; speedup vs baseline: 3.5636x; 1.4318x over previous
//
#include <hip/hip_runtime.h>

// ---------------------------------------------------------------------------
// StyleGAN2-like generator forward. Convs via bf16 MFMA implicit GEMM over
// px-major (channel-contiguous) padded styled activations. B=8, C=512.
// Up-convs decomposed into 4 parity classes (no zero-stuffing).
// ---------------------------------------------------------------------------

#define SQRT2F      1.41421356f
#define MAP_SCALE   4.41941738e-04f   // 0.01/sqrt(512)
#define MOD_SCALE   4.41941738e-02f   // 1/sqrt(512)
#define CONV_SCALE  1.47313913e-02f   // 1/sqrt(512*9)
#define RGB_SCALE   4.41941738e-02f   // 1/sqrt(512)

typedef __attribute__((ext_vector_type(8))) short bf16x8;
typedef __attribute__((ext_vector_type(16))) float f32x16;

__device__ __forceinline__ float bf2f(ushort u) {
    return __uint_as_float(((unsigned)u) << 16);
}
__device__ __forceinline__ ushort f2bf(float f) {
    unsigned u = __float_as_uint(f);
    unsigned r = (u + 0x7FFFu + ((u >> 16) & 1u)) >> 16;
    return (ushort)r;
}
__device__ __forceinline__ void store4bf(ushort* p, float a, float b, float c, float d) {
    union { ushort u[4]; uint2 v; } x;
    x.u[0] = f2bf(a); x.u[1] = f2bf(b); x.u[2] = f2bf(c); x.u[3] = f2bf(d);
    *(uint2*)p = x.v;
}

// ============================ PRNG (JAX threefry) ===========================

__device__ __forceinline__ unsigned rotl32(unsigned x, int r) {
    return (x << r) | (x >> (32 - r));
}

__device__ void threefry2x32(unsigned k0, unsigned k1, unsigned x0, unsigned x1,
                             unsigned& o0, unsigned& o1) {
    unsigned k2 = k0 ^ k1 ^ 0x1BD11BDAu;
    x0 += k0; x1 += k1;
    x0 += x1; x1 = rotl32(x1,13); x1 ^= x0;
    x0 += x1; x1 = rotl32(x1,15); x1 ^= x0;
    x0 += x1; x1 = rotl32(x1,26); x1 ^= x0;
    x0 += x1; x1 = rotl32(x1, 6); x1 ^= x0;
    x0 += k1; x1 += k2 + 1u;
    x0 += x1; x1 = rotl32(x1,17); x1 ^= x0;
    x0 += x1; x1 = rotl32(x1,29); x1 ^= x0;
    x0 += x1; x1 = rotl32(x1,16); x1 ^= x0;
    x0 += x1; x1 = rotl32(x1,24); x1 ^= x0;
    x0 += k2; x1 += k0 + 2u;
    x0 += x1; x1 = rotl32(x1,13); x1 ^= x0;
    x0 += x1; x1 = rotl32(x1,15); x1 ^= x0;
    x0 += x1; x1 = rotl32(x1,26); x1 ^= x0;
    x0 += x1; x1 = rotl32(x1, 6); x1 ^= x0;
    x0 += k0; x1 += k1 + 3u;
    x0 += x1; x1 = rotl32(x1,17); x1 ^= x0;
    x0 += x1; x1 = rotl32(x1,29); x1 ^= x0;
    x0 += x1; x1 = rotl32(x1,16); x1 ^= x0;
    x0 += x1; x1 = rotl32(x1,24); x1 ^= x0;
    x0 += k1; x1 += k2 + 4u;
    x0 += x1; x1 = rotl32(x1,13); x1 ^= x0;
    x0 += x1; x1 = rotl32(x1,15); x1 ^= x0;
    x0 += x1; x1 = rotl32(x1,26); x1 ^= x0;
    x0 += x1; x1 = rotl32(x1, 6); x1 ^= x0;
    x0 += k2; x1 += k0 + 5u;
    o0 = x0; o1 = x1;
}

__device__ float bits_to_normal(unsigned bits) {
    unsigned m = (bits >> 9) | 0x3F800000u;
    float f = __uint_as_float(m) - 1.0f;
    const float lo = -0.99999994f;
    float u = f * 2.0f + lo;
    u = fmaxf(lo, u);
    float w = -log1pf(-u * u);
    float p;
    if (w < 5.0f) {
        w -= 2.5f;
        p = 2.81022636e-08f;
        p = fmaf(p, w, 3.43273939e-07f);
        p = fmaf(p, w, -3.5233877e-06f);
        p = fmaf(p, w, -4.39150654e-06f);
        p = fmaf(p, w, 0.00021858087f);
        p = fmaf(p, w, -0.00125372503f);
        p = fmaf(p, w, -0.00417768164f);
        p = fmaf(p, w, 0.246640727f);
        p = fmaf(p, w, 1.50140941f);
    } else {
        w = sqrtf(w) - 3.0f;
        p = -0.000200214257f;
        p = fmaf(p, w, 0.000100950558f);
        p = fmaf(p, w, 0.00134934322f);
        p = fmaf(p, w, -0.00367342844f);
        p = fmaf(p, w, 0.00573950773f);
        p = fmaf(p, w, -0.0076224613f);
        p = fmaf(p, w, 0.00943887047f);
        p = fmaf(p, w, 1.00167406f);
        p = fmaf(p, w, 2.83297682f);
    }
    return 1.41421354f * (p * u);
}

// counter-mode threefry (jax_threefry_partitionable): bits = out0 ^ out1 at ctr (0,i)
__global__ void noise_kernel(float* __restrict__ nbuf) {
    int g = blockIdx.x * 256 + threadIdx.x;
    if (g >= 21632) return;
    const int off[8] = {0, 128, 640, 1152, 3200, 5248, 13440, 21632};
    int l = 0;
    while (l < 6 && g >= off[l + 1]) l++;
    int i = g - off[l];
    unsigned k0, k1;
    threefry2x32(0u, 7u, 0u, (unsigned)l, k0, k1);
    unsigned b0, b1;
    threefry2x32(k0, k1, 0u, (unsigned)i, b0, b1);
    nbuf[g] = bits_to_normal(b0 ^ b1);
}

// ============================ small linear kernels ==========================

__global__ void pixelnorm_kernel(const float* __restrict__ z, float* __restrict__ out) {
    int b = blockIdx.x;
    int lane = threadIdx.x;
    float v[8];
    float s = 0.f;
    #pragma unroll
    for (int j = 0; j < 8; j++) {
        v[j] = z[b * 512 + lane + (j << 6)];
        s += v[j] * v[j];
    }
    #pragma unroll
    for (int off = 32; off > 0; off >>= 1) s += __shfl_xor(s, off, 64);
    float norm = rsqrtf(s * (1.f / 512.f) + 1e-8f);
    #pragma unroll
    for (int j = 0; j < 8; j++)
        out[b * 512 + lane + (j << 6)] = v[j] * norm;
}

__global__ void dot512_kernel(const float* __restrict__ win, const float* __restrict__ W,
                              const float* __restrict__ bias, float* __restrict__ out,
                              int total, float wscale, float bscale, int mode) {
    int gt = blockIdx.x * blockDim.x + threadIdx.x;
    int wv = gt >> 6;
    int lane = gt & 63;
    if (wv >= total) return;
    int l = wv >> 12;
    int r = wv & 4095;
    int b = r >> 9;
    int o = r & 511;
    const float* wrow = W + ((size_t)(l * 512 + o) << 9);
    const float* xrow = win + ((size_t)b << 9);
    float s = 0.f;
    #pragma unroll
    for (int j = 0; j < 8; j++) {
        int k = lane + (j << 6);
        s += wrow[k] * xrow[k];
    }
    #pragma unroll
    for (int off = 32; off > 0; off >>= 1) s += __shfl_xor(s, off, 64);
    if (lane == 0) {
        float v = s * wscale + bias[l * 512 + o] * bscale;
        if (mode) v = (v > 0.f ? v : 0.2f * v) * SQRT2F;
        out[wv] = v;
    }
}

// weights repack: wb[t][o][i] bf16 (tap flipped if flip) + wsq[o*512+i]
__global__ void wbconv_kernel(const float* __restrict__ cw, int l, int flip,
                              ushort* __restrict__ wb, float* __restrict__ wsq) {
    int idx = blockIdx.x * 256 + threadIdx.x;
    if (idx >= 512 * 512) return;
    int o = idx >> 9, i = idx & 511;
    const float* p = cw + (((size_t)l * 262144) + idx) * 9;
    float w9[9];
    float s = 0.f;
    #pragma unroll
    for (int t = 0; t < 9; t++) { w9[t] = p[t]; s += w9[t] * w9[t]; }
    wsq[idx] = s;
    #pragma unroll
    for (int t = 0; t < 9; t++) {
        int tsrc = flip ? (8 - t) : t;
        wb[((size_t)(t * 512 + o) << 9) + i] = f2bf(w9[tsrc]);
    }
}

__global__ void demod_kernel(const float* __restrict__ wsq, const float* __restrict__ sc,
                             float* __restrict__ dm) {
    int gt = blockIdx.x * blockDim.x + threadIdx.x;
    int wv = gt >> 6;
    int lane = gt & 63;
    if (wv >= 4096) return;
    int b = wv >> 9;
    int o = wv & 511;
    const float* wr = wsq + ((size_t)o << 9);
    const float* sr = sc + ((size_t)b << 9);
    float s = 0.f;
    #pragma unroll
    for (int j = 0; j < 8; j++) {
        int k = lane + (j << 6);
        float sv = sr[k];
        s += wr[k] * sv * sv;
    }
    #pragma unroll
    for (int off = 32; off > 0; off >>= 1) s += __shfl_xor(s, off, 64);
    if (lane == 0) dm[wv] = rsqrtf(s * (1.f / 4608.f) + 1e-8f);
}

// prep l0 input: X0p[8*6][6][512] = styled padded const_input (guards zero)
__global__ void prep0_kernel(const float* __restrict__ cinp, const float* __restrict__ s0,
                             ushort* __restrict__ X0p) {
    int gid = blockIdx.x * 256 + threadIdx.x;
    if (gid >= 8 * 36 * 64) return;
    int grp = gid & 63;
    int r = gid >> 6;
    int b = r / 36, rc = r % 36, row = rc / 6, col = rc % 6;
    int y = row - 1, x = col - 1;
    union { ushort u[8]; bf16x8 v; } pk;
    if (y >= 0 && y < 4 && x >= 0 && x < 4) {
        #pragma unroll
        for (int k = 0; k < 8; k++) {
            int ch = grp * 8 + k;
            pk.u[k] = f2bf(cinp[ch * 16 + y * 4 + x] * s0[b * 512 + ch]);
        }
    } else {
        #pragma unroll
        for (int k = 0; k < 8; k++) pk.u[k] = 0;
    }
    *(bf16x8*)&X0p[(((size_t)(b * 6 + row) * 6 + col) << 9) + grp * 8] = pk.v;
}

// ====================== dense 3x3 conv (MFMA, px-major) =====================
// Xp: [8*(S+2)][(S+2)][512] styled padded input (guards zero).
// Block: 256 thr = 4 n-waves; wave tile m=64 (o) x n=64 (2 cols of 32 px).
// Epilogue: demod+noise+bias+lrelu -> T plain [8][S*S][512];
// if WRITE_UP also styled (snext) padded XU [8*(S+2)][(S+2)][512].
template <int S, int WROWS, bool WRITE_UP>
__global__ __launch_bounds__(256) void conv_dense(
    const ushort* __restrict__ Xp, const ushort* __restrict__ wb,
    const float* __restrict__ dm, const float* __restrict__ nz,
    const float* __restrict__ nstr, const float* __restrict__ bias,
    const float* __restrict__ snext,
    ushort* __restrict__ T, ushort* __restrict__ XU) {
    constexpr int SP = S + 2, P2 = S * S, N = 8 * P2, CIP = 40;
    constexpr int ROWMAX = 8 * SP - 1;
    __shared__ __align__(16) ushort bstage[WROWS * SP * CIP];
    const int tid = threadIdx.x, lane = tid & 63, wv = tid >> 6;
    const int hf = lane >> 5, l31 = lane & 31;
    const int o0 = blockIdx.x * 64;
    const int n0 = blockIdx.y * 256;
    const int R0 = (n0 / P2) * SP + (n0 % P2) / S;

    int pixbase[2], bj[2], rj[2];
    bool validj[2];
    #pragma unroll
    for (int j = 0; j < 2; j++) {
        int n = n0 + wv * 64 + j * 32 + l31;
        validj[j] = n < N;
        int nc = validj[j] ? n : (N - 1);
        int b = nc / P2, r = nc % P2;
        int y = r / S, x = r % S;
        bj[j] = b; rj[j] = r;
        pixbase[j] = ((b * SP + y - R0) * SP + x) * CIP;
    }
    f32x16 acc00 = (f32x16)0.f, acc01 = (f32x16)0.f;
    f32x16 acc10 = (f32x16)0.f, acc11 = (f32x16)0.f;

    for (int i0 = 0; i0 < 512; i0 += 32) {
        __syncthreads();
        constexpr int NVEC = WROWS * SP * 4;
        for (int idx = tid; idx < NVEC; idx += 256) {
            int pc = idx >> 2, jj = idx & 3;
            int rr = pc / SP, cc = pc % SP;
            int Rc = R0 + rr;
            if (Rc > ROWMAX) Rc = ROWMAX;
            *(bf16x8*)&bstage[pc * CIP + jj * 8] =
                *(const bf16x8*)&Xp[(((size_t)Rc * SP + cc) << 9) + i0 + jj * 8];
        }
        __syncthreads();
        #pragma unroll
        for (int t = 0; t < 9; t++) {
            const int toff = ((t / 3) * SP + (t % 3)) * CIP;
            #pragma unroll
            for (int s = 0; s < 2; s++) {
                const int kl = s * 16 + hf * 8;
                bf16x8 bf0 = *(const bf16x8*)&bstage[pixbase[0] + toff + kl];
                bf16x8 bf1 = *(const bf16x8*)&bstage[pixbase[1] + toff + kl];
                const ushort* wp = wb + (((size_t)(t * 512 + o0 + l31)) << 9) + i0 + kl;
                bf16x8 a0 = *(const bf16x8*)wp;
                bf16x8 a1 = *(const bf16x8*)(wp + (32 << 9));
                acc00 = __builtin_amdgcn_mfma_f32_32x32x16_bf16(a0, bf0, acc00, 0, 0, 0);
                acc01 = __builtin_amdgcn_mfma_f32_32x32x16_bf16(a0, bf1, acc01, 0, 0, 0);
                acc10 = __builtin_amdgcn_mfma_f32_32x32x16_bf16(a1, bf0, acc10, 0, 0, 0);
                acc11 = __builtin_amdgcn_mfma_f32_32x32x16_bf16(a1, bf1, acc11, 0, 0, 0);
            }
        }
    }
    float ns = nstr[0];
    #pragma unroll
    for (int j = 0; j < 2; j++) {
        if (!validj[j]) continue;
        int b = bj[j], r = rj[j];
        float nv = nz[b * P2 + r];
        int y = r / S, x = r % S;
        size_t tbase = ((size_t)b * P2 + r) << 9;
        size_t ubase = ((size_t)(b * SP + y + 1) * SP + x + 1) << 9;
        #pragma unroll
        for (int sub = 0; sub < 2; sub++) {
            #pragma unroll
            for (int rq = 0; rq < 4; rq++) {
                int o = o0 + sub * 32 + 4 * hf + 8 * rq;
                float4 d4 = *(const float4*)&dm[b * 512 + o];
                float4 b4 = *(const float4*)&bias[o];
                float vv[4];
                #pragma unroll
                for (int ri = 0; ri < 4; ri++) {
                    float av;
                    if (j == 0) av = (sub == 0) ? acc00[rq * 4 + ri] : acc10[rq * 4 + ri];
                    else        av = (sub == 0) ? acc01[rq * 4 + ri] : acc11[rq * 4 + ri];
                    float v = av * (&d4.x)[ri] * CONV_SCALE + ns * nv + (&b4.x)[ri];
                    vv[ri] = (v > 0.f ? v : 0.2f * v) * SQRT2F;
                }
                store4bf(T + tbase + o, vv[0], vv[1], vv[2], vv[3]);
                if (WRITE_UP) {
                    float4 s4 = *(const float4*)&snext[b * 512 + o];
                    store4bf(XU + ubase + o, vv[0] * s4.x, vv[1] * s4.y,
                             vv[2] * s4.z, vv[3] * s4.w);
                }
            }
        }
    }
}

// =================== up-conv (transposed, parity class) =====================
// Xp: [8*(HIN+2)][(HIN+2)][512] styled padded input.
// Class (PY,PX): out pixels y=2gy+PY, x=2gx+PX of SOUT=2HIN+1 grid.
// Taps: dy in (PY? {1}:{0,2}), dx similarly; weight index t=dy*3+dx (wb pre-flipped);
// input padded row gy+(dy+PY)/2, col gx+(dx+PX)/2.
// Block: 256 thr = 2 m-waves x 2 n-waves (m=128, n=128).
// Writes U plain padded pre-blur [8*(SOUT+2)][(SOUT+2)][512] (v = acc*dem*scale).
template <int HIN, int WROWS, int PY, int PX>
__global__ __launch_bounds__(256) void conv_up(
    const ushort* __restrict__ Xp, const ushort* __restrict__ wb,
    const float* __restrict__ dm, ushort* __restrict__ U) {
    constexpr int SPI = HIN + 2, SOUT = 2 * HIN + 1, SPO = SOUT + 2, CIP = 40;
    constexpr int GY = PY ? HIN : HIN + 1, GX = PX ? HIN : HIN + 1;
    constexpr int NCLS = 8 * GY * GX;
    constexpr int NTY = PY ? 1 : 2, NTX = PX ? 1 : 2;
    constexpr int ROWMAX = 8 * SPI - 1;
    __shared__ __align__(16) ushort bstage[WROWS * SPI * CIP];
    const int tid = threadIdx.x, lane = tid & 63, wv = tid >> 6;
    const int hf = lane >> 5, l31 = lane & 31;
    const int mw = wv >> 1, nw = wv & 1;
    const int o0 = blockIdx.x * 128 + mw * 64;
    const int n0 = blockIdx.y * 128;
    const int R0 = (n0 / (GY * GX)) * SPI + (n0 % (GY * GX)) / GX;

    int pixbase[2], bj[2], gyj[2], gxj[2];
    bool validj[2];
    #pragma unroll
    for (int j = 0; j < 2; j++) {
        int n = n0 + nw * 64 + j * 32 + l31;
        validj[j] = n < NCLS;
        int nc = validj[j] ? n : (NCLS - 1);
        int b = nc / (GY * GX), rem = nc % (GY * GX);
        int gy = rem / GX, gx = rem % GX;
        bj[j] = b; gyj[j] = gy; gxj[j] = gx;
        pixbase[j] = ((b * SPI + gy - R0) * SPI + gx) * CIP;
    }
    f32x16 acc00 = (f32x16)0.f, acc01 = (f32x16)0.f;
    f32x16 acc10 = (f32x16)0.f, acc11 = (f32x16)0.f;

    const int dys[2] = {PY ? 1 : 0, PY ? 1 : 2};
    const int dxs[2] = {PX ? 1 : 0, PX ? 1 : 2};

    for (int i0 = 0; i0 < 512; i0 += 32) {
        __syncthreads();
        constexpr int NVEC = WROWS * SPI * 4;
        for (int idx = tid; idx < NVEC; idx += 256) {
            int pc = idx >> 2, jj = idx & 3;
            int rr = pc / SPI, cc = pc % SPI;
            int Rc = R0 + rr;
            if (Rc > ROWMAX) Rc = ROWMAX;
            *(bf16x8*)&bstage[pc * CIP + jj * 8] =
                *(const bf16x8*)&Xp[(((size_t)Rc * SPI + cc) << 9) + i0 + jj * 8];
        }
        __syncthreads();
        #pragma unroll
        for (int a = 0; a < NTY; a++) {
            #pragma unroll
            for (int c = 0; c < NTX; c++) {
                const int dy = dys[a], dx = dxs[c];
                const int t = dy * 3 + dx;
                const int toff = (((dy + PY) / 2) * SPI + (dx + PX) / 2) * CIP;
                #pragma unroll
                for (int s = 0; s < 2; s++) {
                    const int kl = s * 16 + hf * 8;
                    bf16x8 bf0 = *(const bf16x8*)&bstage[pixbase[0] + toff + kl];
                    bf16x8 bf1 = *(const bf16x8*)&bstage[pixbase[1] + toff + kl];
                    const ushort* wp = wb + (((size_t)(t * 512 + o0 + l31)) << 9) + i0 + kl;
                    bf16x8 a0 = *(const bf16x8*)wp;
                    bf16x8 a1 = *(const bf16x8*)(wp + (32 << 9));
                    acc00 = __builtin_amdgcn_mfma_f32_32x32x16_bf16(a0, bf0, acc00, 0, 0, 0);
                    acc01 = __builtin_amdgcn_mfma_f32_32x32x16_bf16(a0, bf1, acc01, 0, 0, 0);
                    acc10 = __builtin_amdgcn_mfma_f32_32x32x16_bf16(a1, bf0, acc10, 0, 0, 0);
                    acc11 = __builtin_amdgcn_mfma_f32_32x32x16_bf16(a1, bf1, acc11, 0, 0, 0);
                }
            }
        }
    }
    #pragma unroll
    for (int j = 0; j < 2; j++) {
        if (!validj[j]) continue;
        int b = bj[j];
        int y = 2 * gyj[j] + PY, x = 2 * gxj[j] + PX;
        size_t ubase = ((size_t)(b * SPO + y + 1) * SPO + x + 1) << 9;
        #pragma unroll
        for (int sub = 0; sub < 2; sub++) {
            #pragma unroll
            for (int rq = 0; rq < 4; rq++) {
                int o = o0 + sub * 32 + 4 * hf + 8 * rq;
                float4 d4 = *(const float4*)&dm[b * 512 + o];
                float vv[4];
                #pragma unroll
                for (int ri = 0; ri < 4; ri++) {
                    float av;
                    if (j == 0) av = (sub == 0) ? acc00[rq * 4 + ri] : acc10[rq * 4 + ri];
                    else        av = (sub == 0) ? acc01[rq * 4 + ri] : acc11[rq * 4 + ri];
                    vv[ri] = av * (&d4.x)[ri] * CONV_SCALE;
                }
                store4bf(U + ubase + o, vv[0], vv[1], vv[2], vv[3]);
            }
        }
    }
}

// =================== blur 4x4 + noise + bias + lrelu + style ================
// U: [8*(SIN+2)][(SIN+2)][512] padded pre-blur; X: [8*(O+2)][(O+2)][512] styled padded.
template <int SIN>
__global__ void blur_px(const ushort* __restrict__ U, const float* __restrict__ nz,
                        const float* __restrict__ nstr, const float* __restrict__ bias,
                        const float* __restrict__ snext, ushort* __restrict__ X) {
    constexpr int O = SIN - 1, SPI = SIN + 2, SPO = O + 2;
    int gid = blockIdx.x * 256 + threadIdx.x;
    if (gid >= 8 * O * O * 64) return;
    int grp = gid & 63;
    int pxl = gid >> 6;
    int b = pxl / (O * O), r = pxl % (O * O), u = r / O, vcol = r % O;
    const float k1[4] = {0.25f, 0.75f, 0.75f, 0.25f};
    float acc[8];
    #pragma unroll
    for (int k = 0; k < 8; k++) acc[k] = 0.f;
    #pragma unroll
    for (int a = 0; a < 4; a++) {
        int row = b * SPI + u + a;
        #pragma unroll
        for (int c = 0; c < 4; c++) {
            float w = k1[a] * k1[c];
            bf16x8 v = *(const bf16x8*)&U[(((size_t)row * SPI + vcol + c) << 9) + grp * 8];
            #pragma unroll
            for (int k = 0; k < 8; k++) acc[k] += w * bf2f((ushort)v[k]);
        }
    }
    float nsv = nstr[0] * nz[b * O * O + r];
    float4 b0 = *(const float4*)&bias[grp * 8];
    float4 b1 = *(const float4*)&bias[grp * 8 + 4];
    float4 s0 = *(const float4*)&snext[b * 512 + grp * 8];
    float4 s1 = *(const float4*)&snext[b * 512 + grp * 8 + 4];
    union { ushort us[8]; bf16x8 v; } pk;
    #pragma unroll
    for (int k = 0; k < 8; k++) {
        float bk = (k < 4) ? (&b0.x)[k] : (&b1.x)[k - 4];
        float sk = (k < 4) ? (&s0.x)[k] : (&s1.x)[k - 4];
        float v = acc[k] + nsv + bk;
        v = (v > 0.f ? v : 0.2f * v) * SQRT2F;
        pk.us[k] = f2bf(v * sk);
    }
    *(bf16x8*)&X[(((size_t)(b * SPO + u + 1) * SPO + vcol + 1) << 9) + grp * 8] = pk.v;
}

// ======================== skip upsample (up=2, pad 2,1) =====================
template <int H>
__global__ void skipup_kernel(const float* __restrict__ skip, float* __restrict__ out) {
    constexpr int O = 2 * H;
    int idx = blockIdx.x * 256 + threadIdx.x;
    if (idx >= 8 * 3 * O * O) return;
    int px = idx % (O * O);
    int bc = idx / (O * O);
    int u = px / O, v = px % O;
    const float k1[4] = {0.25f, 0.75f, 0.75f, 0.25f};
    const float* src = skip + (size_t)bc * (H * H);
    float acc = 0.f;
    #pragma unroll
    for (int ty = 0; ty < 4; ty++) {
        int r = u + ty - 2;
        if (r < 0 || (r & 1) || (r >> 1) >= H) continue;
        float rsum = 0.f;
        #pragma unroll
        for (int tx = 0; tx < 4; tx++) {
            int cc = v + tx - 2;
            if (cc < 0 || (cc & 1) || (cc >> 1) >= H) continue;
            rsum += k1[tx] * src[(r >> 1) * H + (cc >> 1)];
        }
        acc += k1[ty] * rsum;
    }
    out[(size_t)bc * (O * O) + px] = acc;
}

// ============================ to_rgb (px-major) =============================
__global__ void torgb_px(const ushort* __restrict__ T, int P2,
                         const float* __restrict__ rgbw, const float* __restrict__ srgb,
                         const float* __restrict__ rbias, const float* __restrict__ skipup,
                         float* __restrict__ dst) {
    int b = blockIdx.x;
    int px = blockIdx.y * 4 + (threadIdx.x >> 6);
    int lane = threadIdx.x & 63;
    int c8 = lane * 8;
    bf16x8 v = *(const bf16x8*)&T[(((size_t)b * P2 + px) << 9) + c8];
    float4 sa = *(const float4*)&srgb[b * 512 + c8];
    float4 sb = *(const float4*)&srgb[b * 512 + c8 + 4];
    float xs[8];
    #pragma unroll
    for (int k = 0; k < 8; k++) {
        float sk = (k < 4) ? (&sa.x)[k] : (&sb.x)[k - 4];
        xs[k] = bf2f((ushort)v[k]) * sk;
    }
    float sums[3];
    #pragma unroll
    for (int c = 0; c < 3; c++) {
        float4 w0 = *(const float4*)&rgbw[c * 512 + c8];
        float4 w1 = *(const float4*)&rgbw[c * 512 + c8 + 4];
        float s = 0.f;
        #pragma unroll
        for (int k = 0; k < 8; k++) {
            float wk = (k < 4) ? (&w0.x)[k] : (&w1.x)[k - 4];
            s += xs[k] * wk;
        }
        #pragma unroll
        for (int off = 32; off > 0; off >>= 1) s += __shfl_xor(s, off, 64);
        sums[c] = s;
    }
    if (lane == 0) {
        #pragma unroll
        for (int c = 0; c < 3; c++) {
            float o = sums[c] * RGB_SCALE + rbias[c];
            if (skipup) o += skipup[((size_t)b * 3 + c) * P2 + px];
            dst[((size_t)b * 3 + c) * P2 + px] = o;
        }
    }
}

// ================================ launch ====================================

extern "C" void kernel_launch(void* const* d_in, const int* in_sizes, int n_in,
                              void* d_out, int out_size, void* d_ws, size_t ws_size,
                              hipStream_t stream) {
    const float* z      = (const float*)d_in[0];
    const float* mlp_w  = (const float*)d_in[1];
    const float* mlp_b  = (const float*)d_in[2];
    const float* cinp   = (const float*)d_in[3];
    const float* conv_w = (const float*)d_in[4];
    const float* cmw    = (const float*)d_in[5];
    const float* cmb    = (const float*)d_in[6];
    const float* cbias  = (const float*)d_in[7];
    const float* nstr   = (const float*)d_in[8];
    const float* rgbw   = (const float*)d_in[9];
    const float* rmw    = (const float*)d_in[10];
    const float* rmb    = (const float*)d_in[11];
    const float* rbias  = (const float*)d_in[12];
    float* out = (float*)d_out;
    float* ws = (float*)d_ws;

    // ---- workspace (float-slot offsets) ----
    float* wlatA = ws;                       // 4096
    float* wlatB = ws + 4096;                // 4096
    float* sconv = ws + 8192;                // 7*4096
    float* srgb  = ws + 36864;               // 4*4096
    float* dem   = ws + 53248;               // 7*4096
    float* noise = ws + 81920;               // 21632
    float* skipA = ws + 103552;              // 24576
    float* skipB = ws + 128128;              // 24576
    float* skipU = ws + 152704;              // 24576
    float* wsq   = ws + 177280;              // 262144 -> 439424
    ushort* wbuf = (ushort*)(ws + 439424);   // 2359296 us -> f 1619072
    ushort* A1 = (ushort*)(ws + 1619072);    // 5017600 us -> f 4127872
    ushort* A2 = (ushort*)(ws + 4127872);    // 4734976 us -> f 6495360
    ushort* A3 = (ushort*)(ws + 6495360);    // 4194304 us -> f 8592512

    // arena aliases (lifetimes verified disjoint)
    ushort* X0p = A1;   // 8*6*6*512
    ushort* T0  = A2;   // 8*16*512
    ushort* XU1 = A3;   // 8*6*6*512
    ushort* U1  = A1;   // 8*11*11*512
    ushort* X2  = A2;   // 8*10*10*512
    ushort* T2  = A3;   // 8*64*512
    ushort* XU3 = A1;   // 8*10*10*512
    ushort* U3  = A2;   // 8*19*19*512
    ushort* X4  = A1;   // 8*18*18*512
    ushort* T4  = A2;   // 8*256*512
    ushort* XU5 = A3;   // 8*18*18*512
    ushort* U5  = A1;   // 8*35*35*512
    ushort* X6  = A2;   // 8*34*34*512
    ushort* T6  = A3;   // 8*1024*512

    // mapping network
    pixelnorm_kernel<<<8, 64, 0, stream>>>(z, wlatA);
    float* a = wlatA;
    float* bb = wlatB;
    for (int i = 0; i < 8; i++) {
        dot512_kernel<<<1024, 256, 0, stream>>>(a, mlp_w + (size_t)i * 262144,
                                                mlp_b + i * 512, bb, 4096,
                                                MAP_SCALE, 0.01f, 1);
        float* t = a; a = bb; bb = t;
    }
    dot512_kernel<<<7168, 256, 0, stream>>>(a, cmw, cmb, sconv, 7 * 4096, MOD_SCALE, 1.0f, 0);
    dot512_kernel<<<4096, 256, 0, stream>>>(a, rmw, rmb, srgb, 4 * 4096, MOD_SCALE, 1.0f, 0);
    noise_kernel<<<85, 256, 0, stream>>>(noise);
    prep0_kernel<<<72, 256, 0, stream>>>(cinp, sconv, X0p);

    // ---- layer 0 (dense 4x4) ----
    wbconv_kernel<<<1024, 256, 0, stream>>>(conv_w, 0, 0, wbuf, wsq);
    demod_kernel<<<1024, 256, 0, stream>>>(wsq, sconv, dem);
    hipMemsetAsync(XU1, 0, (size_t)8 * 36 * 512 * 2, stream);
    conv_dense<4, 48, true><<<dim3(8, 1), 256, 0, stream>>>(
        X0p, wbuf, dem, noise, nstr, cbias, sconv + 4096, T0, XU1);
    torgb_px<<<dim3(8, 4), 256, 0, stream>>>(T0, 16, rgbw, srgb, rbias, nullptr, skipA);

    // ---- layer 1 (up 4->9) ----
    wbconv_kernel<<<1024, 256, 0, stream>>>(conv_w, 1, 1, wbuf, wsq);
    demod_kernel<<<1024, 256, 0, stream>>>(wsq, sconv + 4096, dem + 4096);
    hipMemsetAsync(U1, 0, (size_t)8 * 121 * 512 * 2, stream);
    conv_up<4, 48, 0, 0><<<dim3(4, 2), 256, 0, stream>>>(XU1, wbuf, dem + 4096, U1);
    conv_up<4, 48, 0, 1><<<dim3(4, 2), 256, 0, stream>>>(XU1, wbuf, dem + 4096, U1);
    conv_up<4, 48, 1, 0><<<dim3(4, 2), 256, 0, stream>>>(XU1, wbuf, dem + 4096, U1);
    conv_up<4, 48, 1, 1><<<dim3(4, 1), 256, 0, stream>>>(XU1, wbuf, dem + 4096, U1);
    hipMemsetAsync(X2, 0, (size_t)8 * 100 * 512 * 2, stream);
    blur_px<9><<<128, 256, 0, stream>>>(U1, noise + 128, nstr + 1, cbias + 512,
                                        sconv + 2 * 4096, X2);

    // ---- layer 2 (dense 8x8) ----
    wbconv_kernel<<<1024, 256, 0, stream>>>(conv_w, 2, 0, wbuf, wsq);
    demod_kernel<<<1024, 256, 0, stream>>>(wsq, sconv + 2 * 4096, dem + 2 * 4096);
    hipMemsetAsync(XU3, 0, (size_t)8 * 100 * 512 * 2, stream);
    conv_dense<8, 40, true><<<dim3(8, 2), 256, 0, stream>>>(
        X2, wbuf, dem + 2 * 4096, noise + 640, nstr + 2, cbias + 2 * 512,
        sconv + 3 * 4096, T2, XU3);
    skipup_kernel<4><<<6, 256, 0, stream>>>(skipA, skipU);
    torgb_px<<<dim3(8, 16), 256, 0, stream>>>(T2, 64, rgbw + 1536, srgb + 4096,
                                              rbias + 3, skipU, skipB);

    // ---- layer 3 (up 8->17) ----
    wbconv_kernel<<<1024, 256, 0, stream>>>(conv_w, 3, 1, wbuf, wsq);
    demod_kernel<<<1024, 256, 0, stream>>>(wsq, sconv + 3 * 4096, dem + 3 * 4096);
    hipMemsetAsync(U3, 0, (size_t)8 * 361 * 512 * 2, stream);
    conv_up<8, 24, 0, 0><<<dim3(4, 6), 256, 0, stream>>>(XU3, wbuf, dem + 3 * 4096, U3);
    conv_up<8, 24, 0, 1><<<dim3(4, 5), 256, 0, stream>>>(XU3, wbuf, dem + 3 * 4096, U3);
    conv_up<8, 24, 1, 0><<<dim3(4, 5), 256, 0, stream>>>(XU3, wbuf, dem + 3 * 4096, U3);
    conv_up<8, 24, 1, 1><<<dim3(4, 4), 256, 0, stream>>>(XU3, wbuf, dem + 3 * 4096, U3);
    hipMemsetAsync(X4, 0, (size_t)8 * 324 * 512 * 2, stream);
    blur_px<17><<<512, 256, 0, stream>>>(U3, noise + 1152, nstr + 3, cbias + 3 * 512,
                                         sconv + 4 * 4096, X4);

    // ---- layer 4 (dense 16x16) ----
    wbconv_kernel<<<1024, 256, 0, stream>>>(conv_w, 4, 0, wbuf, wsq);
    demod_kernel<<<1024, 256, 0, stream>>>(wsq, sconv + 4 * 4096, dem + 4 * 4096);
    hipMemsetAsync(XU5, 0, (size_t)8 * 324 * 512 * 2, stream);
    conv_dense<16, 18, true><<<dim3(8, 8), 256, 0, stream>>>(
        X4, wbuf, dem + 4 * 4096, noise + 3200, nstr + 4, cbias + 4 * 512,
        sconv + 5 * 4096, T4, XU5);
    skipup_kernel<8><<<24, 256, 0, stream>>>(skipB, skipU);
    torgb_px<<<dim3(8, 64), 256, 0, stream>>>(T4, 256, rgbw + 2 * 1536, srgb + 2 * 4096,
                                              rbias + 6, skipU, skipA);

    // ---- layer 5 (up 16->33) ----
    wbconv_kernel<<<1024, 256, 0, stream>>>(conv_w, 5, 1, wbuf, wsq);
    demod_kernel<<<1024, 256, 0, stream>>>(wsq, sconv + 5 * 4096, dem + 5 * 4096);
    hipMemsetAsync(U5, 0, (size_t)8 * 1225 * 512 * 2, stream);
    conv_up<16, 12, 0, 0><<<dim3(4, 19), 256, 0, stream>>>(XU5, wbuf, dem + 5 * 4096, U5);
    conv_up<16, 12, 0, 1><<<dim3(4, 17), 256, 0, stream>>>(XU5, wbuf, dem + 5 * 4096, U5);
    conv_up<16, 12, 1, 0><<<dim3(4, 17), 256, 0, stream>>>(XU5, wbuf, dem + 5 * 4096, U5);
    conv_up<16, 12, 1, 1><<<dim3(4, 16), 256, 0, stream>>>(XU5, wbuf, dem + 5 * 4096, U5);
    hipMemsetAsync(X6, 0, (size_t)8 * 1156 * 512 * 2, stream);
    blur_px<33><<<2048, 256, 0, stream>>>(U5, noise + 5248, nstr + 5, cbias + 5 * 512,
                                          sconv + 6 * 4096, X6);

    // ---- layer 6 (dense 32x32) ----
    wbconv_kernel<<<1024, 256, 0, stream>>>(conv_w, 6, 0, wbuf, wsq);
    demod_kernel<<<1024, 256, 0, stream>>>(wsq, sconv + 6 * 4096, dem + 6 * 4096);
    conv_dense<32, 10, false><<<dim3(8, 32), 256, 0, stream>>>(
        X6, wbuf, dem + 6 * 4096, noise + 13440, nstr + 6, cbias + 6 * 512,
        nullptr, T6, nullptr);
    skipup_kernel<16><<<96, 256, 0, stream>>>(skipA, skipU);
    torgb_px<<<dim3(8, 256), 256, 0, stream>>>(T6, 1024, rgbw + 3 * 1536, srgb + 3 * 4096,
                                               rbias + 9, skipU, out);
}

// Round 7
// 821.500 us; speedup vs baseline: 4.9736x; 1.3957x over previous
//
#include <hip/hip_runtime.h>

// ---------------------------------------------------------------------------
// StyleGAN2-like generator forward. Convs via bf16 MFMA implicit GEMM over
// px-major padded styled activations, A+B staged in LDS with reg-prefetch.
// B=8, C=512, output [8,3,32,32] f32.
// ---------------------------------------------------------------------------

#define SQRT2F      1.41421356f
#define MAP_SCALE   4.41941738e-04f   // 0.01/sqrt(512)
#define MOD_SCALE   4.41941738e-02f   // 1/sqrt(512)
#define CONV_SCALE  1.47313913e-02f   // 1/sqrt(512*9)
#define RGB_SCALE   4.41941738e-02f   // 1/sqrt(512)

typedef __attribute__((ext_vector_type(8))) short bf16x8;
typedef __attribute__((ext_vector_type(16))) float f32x16;

__device__ __forceinline__ float bf2f(ushort u) {
    return __uint_as_float(((unsigned)u) << 16);
}
__device__ __forceinline__ ushort f2bf(float f) {
    unsigned u = __float_as_uint(f);
    unsigned r = (u + 0x7FFFu + ((u >> 16) & 1u)) >> 16;
    return (ushort)r;
}
__device__ __forceinline__ void store4bf(ushort* p, float a, float b, float c, float d) {
    union { ushort u[4]; uint2 v; } x;
    x.u[0] = f2bf(a); x.u[1] = f2bf(b); x.u[2] = f2bf(c); x.u[3] = f2bf(d);
    *(uint2*)p = x.v;
}

// ============================ PRNG (JAX threefry) ===========================

__device__ __forceinline__ unsigned rotl32(unsigned x, int r) {
    return (x << r) | (x >> (32 - r));
}

__device__ void threefry2x32(unsigned k0, unsigned k1, unsigned x0, unsigned x1,
                             unsigned& o0, unsigned& o1) {
    unsigned k2 = k0 ^ k1 ^ 0x1BD11BDAu;
    x0 += k0; x1 += k1;
    x0 += x1; x1 = rotl32(x1,13); x1 ^= x0;
    x0 += x1; x1 = rotl32(x1,15); x1 ^= x0;
    x0 += x1; x1 = rotl32(x1,26); x1 ^= x0;
    x0 += x1; x1 = rotl32(x1, 6); x1 ^= x0;
    x0 += k1; x1 += k2 + 1u;
    x0 += x1; x1 = rotl32(x1,17); x1 ^= x0;
    x0 += x1; x1 = rotl32(x1,29); x1 ^= x0;
    x0 += x1; x1 = rotl32(x1,16); x1 ^= x0;
    x0 += x1; x1 = rotl32(x1,24); x1 ^= x0;
    x0 += k2; x1 += k0 + 2u;
    x0 += x1; x1 = rotl32(x1,13); x1 ^= x0;
    x0 += x1; x1 = rotl32(x1,15); x1 ^= x0;
    x0 += x1; x1 = rotl32(x1,26); x1 ^= x0;
    x0 += x1; x1 = rotl32(x1, 6); x1 ^= x0;
    x0 += k0; x1 += k1 + 3u;
    x0 += x1; x1 = rotl32(x1,17); x1 ^= x0;
    x0 += x1; x1 = rotl32(x1,29); x1 ^= x0;
    x0 += x1; x1 = rotl32(x1,16); x1 ^= x0;
    x0 += x1; x1 = rotl32(x1,24); x1 ^= x0;
    x0 += k1; x1 += k2 + 4u;
    x0 += x1; x1 = rotl32(x1,13); x1 ^= x0;
    x0 += x1; x1 = rotl32(x1,15); x1 ^= x0;
    x0 += x1; x1 = rotl32(x1,26); x1 ^= x0;
    x0 += x1; x1 = rotl32(x1, 6); x1 ^= x0;
    x0 += k2; x1 += k0 + 5u;
    o0 = x0; o1 = x1;
}

__device__ float bits_to_normal(unsigned bits) {
    unsigned m = (bits >> 9) | 0x3F800000u;
    float f = __uint_as_float(m) - 1.0f;
    const float lo = -0.99999994f;
    float u = f * 2.0f + lo;
    u = fmaxf(lo, u);
    float w = -log1pf(-u * u);
    float p;
    if (w < 5.0f) {
        w -= 2.5f;
        p = 2.81022636e-08f;
        p = fmaf(p, w, 3.43273939e-07f);
        p = fmaf(p, w, -3.5233877e-06f);
        p = fmaf(p, w, -4.39150654e-06f);
        p = fmaf(p, w, 0.00021858087f);
        p = fmaf(p, w, -0.00125372503f);
        p = fmaf(p, w, -0.00417768164f);
        p = fmaf(p, w, 0.246640727f);
        p = fmaf(p, w, 1.50140941f);
    } else {
        w = sqrtf(w) - 3.0f;
        p = -0.000200214257f;
        p = fmaf(p, w, 0.000100950558f);
        p = fmaf(p, w, 0.00134934322f);
        p = fmaf(p, w, -0.00367342844f);
        p = fmaf(p, w, 0.00573950773f);
        p = fmaf(p, w, -0.0076224613f);
        p = fmaf(p, w, 0.00943887047f);
        p = fmaf(p, w, 1.00167406f);
        p = fmaf(p, w, 2.83297682f);
    }
    return 1.41421354f * (p * u);
}

__global__ void noise_kernel(float* __restrict__ nbuf) {
    int g = blockIdx.x * 256 + threadIdx.x;
    if (g >= 21632) return;
    const int off[8] = {0, 128, 640, 1152, 3200, 5248, 13440, 21632};
    int l = 0;
    while (l < 6 && g >= off[l + 1]) l++;
    int i = g - off[l];
    unsigned k0, k1;
    threefry2x32(0u, 7u, 0u, (unsigned)l, k0, k1);
    unsigned b0, b1;
    threefry2x32(k0, k1, 0u, (unsigned)i, b0, b1);
    nbuf[g] = bits_to_normal(b0 ^ b1);
}

// ============================ small linear kernels ==========================

__global__ void pixelnorm_kernel(const float* __restrict__ z, float* __restrict__ out) {
    int b = blockIdx.x;
    int lane = threadIdx.x;
    float v[8];
    float s = 0.f;
    #pragma unroll
    for (int j = 0; j < 8; j++) {
        v[j] = z[b * 512 + lane + (j << 6)];
        s += v[j] * v[j];
    }
    #pragma unroll
    for (int off = 32; off > 0; off >>= 1) s += __shfl_xor(s, off, 64);
    float norm = rsqrtf(s * (1.f / 512.f) + 1e-8f);
    #pragma unroll
    for (int j = 0; j < 8; j++)
        out[b * 512 + lane + (j << 6)] = v[j] * norm;
}

__global__ void dot512_kernel(const float* __restrict__ win, const float* __restrict__ W,
                              const float* __restrict__ bias, float* __restrict__ out,
                              int total, float wscale, float bscale, int mode) {
    int gt = blockIdx.x * blockDim.x + threadIdx.x;
    int wv = gt >> 6;
    int lane = gt & 63;
    if (wv >= total) return;
    int l = wv >> 12;
    int r = wv & 4095;
    int b = r >> 9;
    int o = r & 511;
    const float* wrow = W + ((size_t)(l * 512 + o) << 9);
    const float* xrow = win + ((size_t)b << 9);
    float s = 0.f;
    #pragma unroll
    for (int j = 0; j < 8; j++) {
        int k = lane + (j << 6);
        s += wrow[k] * xrow[k];
    }
    #pragma unroll
    for (int off = 32; off > 0; off >>= 1) s += __shfl_xor(s, off, 64);
    if (lane == 0) {
        float v = s * wscale + bias[l * 512 + o] * bscale;
        if (mode) v = (v > 0.f ? v : 0.2f * v) * SQRT2F;
        out[wv] = v;
    }
}

// all-layer weight repack: wb7[l][t][o][i] bf16 (flip for l=1,3,5) + wsq7[l][o][i]
__global__ void wbconv_all(const float* __restrict__ cw, ushort* __restrict__ wb7,
                           float* __restrict__ wsq7) {
    int gid = blockIdx.x * 256 + threadIdx.x;
    if (gid >= 7 * 262144) return;
    int l = gid >> 18;
    int idx = gid & 262143;
    int o = idx >> 9, i = idx & 511;
    int flip = (l == 1 || l == 3 || l == 5);
    const float* p = cw + (size_t)gid * 9;
    float w9[9];
    float s = 0.f;
    #pragma unroll
    for (int t = 0; t < 9; t++) { w9[t] = p[t]; s += w9[t] * w9[t]; }
    wsq7[gid] = s;
    ushort* wb = wb7 + (size_t)l * 2359296;
    #pragma unroll
    for (int t = 0; t < 9; t++) {
        int tsrc = flip ? (8 - t) : t;
        wb[((size_t)(t * 512 + o) << 9) + i] = f2bf(w9[tsrc]);
    }
}

// all-layer demod: dm[l][b][o]
__global__ void demod_all(const float* __restrict__ wsq7, const float* __restrict__ sc,
                          float* __restrict__ dm) {
    int gt = blockIdx.x * blockDim.x + threadIdx.x;
    int wv = gt >> 6;
    int lane = gt & 63;
    if (wv >= 7 * 4096) return;
    int l = wv >> 12, b = (wv >> 9) & 7, o = wv & 511;
    const float* wr = wsq7 + (size_t)l * 262144 + ((size_t)o << 9);
    const float* sr = sc + l * 4096 + (b << 9);
    float s = 0.f;
    #pragma unroll
    for (int j = 0; j < 8; j++) {
        int k = lane + (j << 6);
        float sv = sr[k];
        s += wr[k] * sv * sv;
    }
    #pragma unroll
    for (int off = 32; off > 0; off >>= 1) s += __shfl_xor(s, off, 64);
    if (lane == 0) dm[wv] = rsqrtf(s * (1.f / 4608.f) + 1e-8f);
}

// prep l0 input: X0p[8*6][6][512] = styled padded const_input (guards zero)
__global__ void prep0_kernel(const float* __restrict__ cinp, const float* __restrict__ s0,
                             ushort* __restrict__ X0p) {
    int gid = blockIdx.x * 256 + threadIdx.x;
    if (gid >= 8 * 36 * 64) return;
    int grp = gid & 63;
    int r = gid >> 6;
    int b = r / 36, rc = r % 36, row = rc / 6, col = rc % 6;
    int y = row - 1, x = col - 1;
    union { ushort u[8]; bf16x8 v; } pk;
    if (y >= 0 && y < 4 && x >= 0 && x < 4) {
        #pragma unroll
        for (int k = 0; k < 8; k++) {
            int ch = grp * 8 + k;
            pk.u[k] = f2bf(cinp[ch * 16 + y * 4 + x] * s0[b * 512 + ch]);
        }
    } else {
        #pragma unroll
        for (int k = 0; k < 8; k++) pk.u[k] = 0;
    }
    *(bf16x8*)&X0p[(((size_t)(b * 6 + row) * 6 + col) << 9) + grp * 8] = pk.v;
}

// ================= old-style dense conv (A from global) — l0 only ===========
template <int S, int WROWS, bool WRITE_UP>
__global__ __launch_bounds__(256) void conv_dense_s(
    const ushort* __restrict__ Xp, const ushort* __restrict__ wb,
    const float* __restrict__ dm, const float* __restrict__ nz,
    const float* __restrict__ nstr, const float* __restrict__ bias,
    const float* __restrict__ snext,
    ushort* __restrict__ T, ushort* __restrict__ XU) {
    constexpr int SP = S + 2, P2 = S * S, N = 8 * P2, CIP = 40;
    constexpr int ROWMAX = 8 * SP - 1;
    __shared__ __align__(16) ushort bstage[WROWS * SP * CIP];
    const int tid = threadIdx.x, lane = tid & 63, wv = tid >> 6;
    const int hf = lane >> 5, l31 = lane & 31;
    const int o0 = blockIdx.x * 64;
    const int n0 = blockIdx.y * 256;
    const int R0 = (n0 / P2) * SP + (n0 % P2) / S;

    int pixbase[2], bj[2], rj[2];
    bool validj[2];
    #pragma unroll
    for (int j = 0; j < 2; j++) {
        int n = n0 + wv * 64 + j * 32 + l31;
        validj[j] = n < N;
        int nc = validj[j] ? n : (N - 1);
        int b = nc / P2, r = nc % P2;
        int y = r / S, x = r % S;
        bj[j] = b; rj[j] = r;
        pixbase[j] = ((b * SP + y - R0) * SP + x) * CIP;
    }
    f32x16 acc00 = (f32x16)0.f, acc01 = (f32x16)0.f;
    f32x16 acc10 = (f32x16)0.f, acc11 = (f32x16)0.f;

    for (int i0 = 0; i0 < 512; i0 += 32) {
        __syncthreads();
        constexpr int NVEC = WROWS * SP * 4;
        for (int idx = tid; idx < NVEC; idx += 256) {
            int pc = idx >> 2, jj = idx & 3;
            int rr = pc / SP, cc = pc % SP;
            int Rc = R0 + rr;
            if (Rc > ROWMAX) Rc = ROWMAX;
            *(bf16x8*)&bstage[pc * CIP + jj * 8] =
                *(const bf16x8*)&Xp[(((size_t)Rc * SP + cc) << 9) + i0 + jj * 8];
        }
        __syncthreads();
        #pragma unroll
        for (int t = 0; t < 9; t++) {
            const int toff = ((t / 3) * SP + (t % 3)) * CIP;
            #pragma unroll
            for (int s = 0; s < 2; s++) {
                const int kl = s * 16 + hf * 8;
                bf16x8 bf0 = *(const bf16x8*)&bstage[pixbase[0] + toff + kl];
                bf16x8 bf1 = *(const bf16x8*)&bstage[pixbase[1] + toff + kl];
                const ushort* wp = wb + (((size_t)(t * 512 + o0 + l31)) << 9) + i0 + kl;
                bf16x8 a0 = *(const bf16x8*)wp;
                bf16x8 a1 = *(const bf16x8*)(wp + (32 << 9));
                acc00 = __builtin_amdgcn_mfma_f32_32x32x16_bf16(a0, bf0, acc00, 0, 0, 0);
                acc01 = __builtin_amdgcn_mfma_f32_32x32x16_bf16(a0, bf1, acc01, 0, 0, 0);
                acc10 = __builtin_amdgcn_mfma_f32_32x32x16_bf16(a1, bf0, acc10, 0, 0, 0);
                acc11 = __builtin_amdgcn_mfma_f32_32x32x16_bf16(a1, bf1, acc11, 0, 0, 0);
            }
        }
    }
    float ns = nstr[0];
    #pragma unroll
    for (int j = 0; j < 2; j++) {
        if (!validj[j]) continue;
        int b = bj[j], r = rj[j];
        float nv = nz[b * P2 + r];
        int y = r / S, x = r % S;
        size_t tbase = ((size_t)b * P2 + r) << 9;
        size_t ubase = ((size_t)(b * SP + y + 1) * SP + x + 1) << 9;
        #pragma unroll
        for (int sub = 0; sub < 2; sub++) {
            #pragma unroll
            for (int rq = 0; rq < 4; rq++) {
                int o = o0 + sub * 32 + 4 * hf + 8 * rq;
                float4 d4 = *(const float4*)&dm[b * 512 + o];
                float4 b4 = *(const float4*)&bias[o];
                float vv[4];
                #pragma unroll
                for (int ri = 0; ri < 4; ri++) {
                    float av;
                    if (j == 0) av = (sub == 0) ? acc00[rq * 4 + ri] : acc10[rq * 4 + ri];
                    else        av = (sub == 0) ? acc01[rq * 4 + ri] : acc11[rq * 4 + ri];
                    float v = av * (&d4.x)[ri] * CONV_SCALE + ns * nv + (&b4.x)[ri];
                    vv[ri] = (v > 0.f ? v : 0.2f * v) * SQRT2F;
                }
                store4bf(T + tbase + o, vv[0], vv[1], vv[2], vv[3]);
                if (WRITE_UP) {
                    float4 s4 = *(const float4*)&snext[b * 512 + o];
                    store4bf(XU + ubase + o, vv[0] * s4.x, vv[1] * s4.y,
                             vv[2] * s4.z, vv[3] * s4.w);
                }
            }
        }
    }
}

// ============== dense conv v2: A+B in LDS, reg-prefetch, opt. K-split =======
template <int S, int NTILE, int WROWS, int KS, bool WUP>
__global__ __launch_bounds__(256, 2) void conv_dense2(
    const ushort* __restrict__ Xp, const ushort* __restrict__ wb,
    const float* __restrict__ dm, const float* __restrict__ nz,
    const float* __restrict__ nstr, const float* __restrict__ bias,
    const float* __restrict__ snext,
    ushort* __restrict__ T, ushort* __restrict__ XU, float* __restrict__ Pp) {
    constexpr int SP = S + 2, P2 = S * S, N = 8 * P2;
    constexpr int JCOLS = NTILE / 128;
    constexpr int ASZ = 9 * 4 * 64 * 8;          // 18432 us, k-group-major
    constexpr int NBU = WROWS * SP * 4;
    constexpr int NBT = (NBU + 255) / 256;
    constexpr int ROWMAX = 8 * SP - 1;
    constexpr int CK = 16 / KS;
    __shared__ __align__(16) ushort lds[ASZ + WROWS * SP * 40];

    const int tid = threadIdx.x, lane = tid & 63, nw = tid >> 6;
    const int hf = lane >> 5, l31 = lane & 31;
    const int o0 = blockIdx.x * 64;
    const int n0 = blockIdx.y * NTILE;
    const int ks = blockIdx.z;
    const int R0 = (n0 / P2) * SP + (n0 % P2) / S;
    const int ao = tid & 63, ai = tid >> 6;      // A staging: o, k-group

    int pixbase[JCOLS], nj[JCOLS];
    #pragma unroll
    for (int j = 0; j < JCOLS; j++) {
        int n = n0 + nw * (NTILE / 4) + j * 32 + l31;
        nj[j] = n;
        int b = n / P2, r = n % P2;
        int y = r / S, x = r % S;
        pixbase[j] = ((b * SP + y - R0) * SP + x) * 40;
    }
    f32x16 acc[JCOLS][2];
    #pragma unroll
    for (int j = 0; j < JCOLS; j++) { acc[j][0] = (f32x16)0.f; acc[j][1] = (f32x16)0.f; }

    uint4 apf[9];
    uint4 bpf[NBT];
    auto loadA = [&](int i0c) {
        #pragma unroll
        for (int r = 0; r < 9; r++)
            apf[r] = *(const uint4*)(wb + (((size_t)(r * 512 + o0 + ao)) << 9) + i0c + ai * 8);
    };
    auto storeA = [&]() {
        #pragma unroll
        for (int r = 0; r < 9; r++)
            *(uint4*)&lds[((r * 4 + ai) * 64 + ao) * 8] = apf[r];
    };
    auto loadB = [&](int i0c) {
        #pragma unroll
        for (int r = 0; r < NBT; r++) {
            int idx = tid + 256 * r;
            if (idx < NBU) {
                int pc = idx >> 2, jj = idx & 3;
                int rr = pc / SP, cc = pc % SP;
                int Rc = R0 + rr; if (Rc > ROWMAX) Rc = ROWMAX;
                bpf[r] = *(const uint4*)(Xp + (((size_t)(Rc * SP + cc)) << 9) + i0c + jj * 8);
            }
        }
    };
    auto storeB = [&]() {
        #pragma unroll
        for (int r = 0; r < NBT; r++) {
            int idx = tid + 256 * r;
            if (idx < NBU) {
                int pc = idx >> 2, jj = idx & 3;
                *(uint4*)&lds[ASZ + pc * 40 + jj * 8] = bpf[r];
            }
        }
    };

    const int ibase = ks * CK * 32;
    loadA(ibase); loadB(ibase);
    for (int c = 0; c < CK; c++) {
        if (c) __syncthreads();
        storeA(); storeB();
        __syncthreads();
        if (c + 1 < CK) { loadA(ibase + (c + 1) * 32); loadB(ibase + (c + 1) * 32); }
        #pragma unroll
        for (int t = 0; t < 9; t++) {
            const int toffB = ((t / 3) * SP + (t % 3)) * 40;
            #pragma unroll
            for (int s = 0; s < 2; s++) {
                const int kl = s * 16 + hf * 8;
                bf16x8 a0 = *(const bf16x8*)&lds[((t * 4 + s * 2 + hf) * 64 + l31) * 8];
                bf16x8 a1 = *(const bf16x8*)&lds[((t * 4 + s * 2 + hf) * 64 + 32 + l31) * 8];
                #pragma unroll
                for (int j = 0; j < JCOLS; j++) {
                    bf16x8 bf = *(const bf16x8*)&lds[ASZ + pixbase[j] + toffB + kl];
                    acc[j][0] = __builtin_amdgcn_mfma_f32_32x32x16_bf16(a0, bf, acc[j][0], 0, 0, 0);
                    acc[j][1] = __builtin_amdgcn_mfma_f32_32x32x16_bf16(a1, bf, acc[j][1], 0, 0, 0);
                }
            }
        }
    }

    if constexpr (KS > 1) {
        #pragma unroll
        for (int j = 0; j < JCOLS; j++) {
            float* pb = Pp + (((size_t)(ks * N + nj[j])) << 9) + o0;
            #pragma unroll
            for (int sub = 0; sub < 2; sub++) {
                #pragma unroll
                for (int rq = 0; rq < 4; rq++) {
                    float4 v = make_float4(acc[j][sub][rq * 4 + 0], acc[j][sub][rq * 4 + 1],
                                           acc[j][sub][rq * 4 + 2], acc[j][sub][rq * 4 + 3]);
                    *(float4*)&pb[sub * 32 + 4 * hf + 8 * rq] = v;
                }
            }
        }
        return;
    }
    float ns = nstr[0];
    #pragma unroll
    for (int j = 0; j < JCOLS; j++) {
        int n = nj[j], b = n / P2, r = n % P2;
        float nv = nz[b * P2 + r];
        int y = r / S, x = r % S;
        size_t tbase = (size_t)n << 9;
        size_t ubase = ((size_t)(b * SP + y + 1) * SP + x + 1) << 9;
        #pragma unroll
        for (int sub = 0; sub < 2; sub++) {
            #pragma unroll
            for (int rq = 0; rq < 4; rq++) {
                int o = o0 + sub * 32 + 4 * hf + 8 * rq;
                float4 d4 = *(const float4*)&dm[b * 512 + o];
                float4 b4 = *(const float4*)&bias[o];
                float vv[4];
                #pragma unroll
                for (int ri = 0; ri < 4; ri++) {
                    float v = acc[j][sub][rq * 4 + ri] * (&d4.x)[ri] * CONV_SCALE
                              + ns * nv + (&b4.x)[ri];
                    vv[ri] = (v > 0.f ? v : 0.2f * v) * SQRT2F;
                }
                store4bf(T + tbase + o, vv[0], vv[1], vv[2], vv[3]);
                if (WUP) {
                    float4 s4 = *(const float4*)&snext[b * 512 + o];
                    store4bf(XU + ubase + o, vv[0] * s4.x, vv[1] * s4.y,
                             vv[2] * s4.z, vv[3] * s4.w);
                }
            }
        }
    }
}

// ============ K-split combine + epilogue (dense layers l2, l4) ==============
template <int S, int KS, bool WUP>
__global__ void combine_dense(const float* __restrict__ Pp, const float* __restrict__ dm,
                              const float* __restrict__ nz, const float* __restrict__ nstr,
                              const float* __restrict__ bias, const float* __restrict__ snext,
                              ushort* __restrict__ T, ushort* __restrict__ XU) {
    constexpr int P2 = S * S, N = 8 * P2, SP = S + 2;
    int gid = blockIdx.x * 256 + threadIdx.x;
    int n = gid >> 7, og = (gid & 127) << 2;
    float4 sm = make_float4(0.f, 0.f, 0.f, 0.f);
    #pragma unroll
    for (int k = 0; k < KS; k++) {
        float4 p = *(const float4*)&Pp[(((size_t)(k * N + n)) << 9) + og];
        sm.x += p.x; sm.y += p.y; sm.z += p.z; sm.w += p.w;
    }
    int b = n / P2, r = n % P2;
    float nsv = nstr[0] * nz[b * P2 + r];
    float4 d4 = *(const float4*)&dm[b * 512 + og];
    float4 b4 = *(const float4*)&bias[og];
    float vv[4];
    const float* sp = &sm.x;
    #pragma unroll
    for (int i = 0; i < 4; i++) {
        float v = sp[i] * (&d4.x)[i] * CONV_SCALE + nsv + (&b4.x)[i];
        vv[i] = (v > 0.f ? v : 0.2f * v) * SQRT2F;
    }
    store4bf(&T[((size_t)n << 9) + og], vv[0], vv[1], vv[2], vv[3]);
    if (WUP) {
        int y = r / S, x = r % S;
        float4 s4 = *(const float4*)&snext[b * 512 + og];
        store4bf(&XU[(((size_t)(b * SP + y + 1) * SP + x + 1) << 9) + og],
                 vv[0] * s4.x, vv[1] * s4.y, vv[2] * s4.z, vv[3] * s4.w);
    }
}

// ========= up-conv v2 (all 4 parity classes in one launch, LDS A+B) =========
template <int HIN, int NTILE, int WRW>
__global__ __launch_bounds__(256, 2) void conv_up2(
    const ushort* __restrict__ Xp, const ushort* __restrict__ wb,
    const float* __restrict__ dm, ushort* __restrict__ U) {
    constexpr int SPI = HIN + 2, SOUT = 2 * HIN + 1, SPO = SOUT + 2;
    constexpr int JCOLS = NTILE / 128;
    constexpr int ASZ = 4 * 4 * 64 * 8;          // 8192 us
    constexpr int NBU = WRW * SPI * 4;
    constexpr int NBT = (NBU + 255) / 256;
    constexpr int ROWMAX = 8 * SPI - 1;
    __shared__ __align__(16) ushort lds[ASZ + WRW * SPI * 40];

    const int py = blockIdx.z >> 1, pxp = blockIdx.z & 1;
    const int GY = py ? HIN : HIN + 1, GX = pxp ? HIN : HIN + 1;
    const int GG = GY * GX, NCLS = 8 * GG;
    const int NTY = py ? 1 : 2, NTX = pxp ? 1 : 2, NT = NTY * NTX;
    const int n0 = blockIdx.y * NTILE;
    if (n0 >= NCLS) return;

    int taplist[4], toffs[4];
    {
        int k = 0;
        #pragma unroll
        for (int a2 = 0; a2 < 2; a2++) {
            if (a2 >= NTY) break;
            int dy = py ? 1 : a2 * 2;
            #pragma unroll
            for (int c2 = 0; c2 < 2; c2++) {
                if (c2 >= NTX) break;
                int dx = pxp ? 1 : c2 * 2;
                taplist[k] = dy * 3 + dx;
                toffs[k] = (((dy + py) >> 1) * SPI + ((dx + pxp) >> 1)) * 40;
                k++;
            }
        }
        for (; k < 4; k++) { taplist[k] = 0; toffs[k] = 0; }
    }

    const int tid = threadIdx.x, lane = tid & 63, nw = tid >> 6;
    const int hf = lane >> 5, l31 = lane & 31;
    const int o0 = blockIdx.x * 64;
    const int R0 = (n0 / GG) * SPI + (n0 % GG) / GX;
    const int ao = tid & 63, ai = tid >> 6;

    int pixbase[JCOLS], bj[JCOLS], gyj[JCOLS], gxj[JCOLS];
    bool validj[JCOLS];
    #pragma unroll
    for (int j = 0; j < JCOLS; j++) {
        int n = n0 + nw * (NTILE / 4) + j * 32 + l31;
        validj[j] = n < NCLS;
        int nc = validj[j] ? n : (NCLS - 1);
        int b = nc / GG, rem = nc % GG;
        int gy = rem / GX, gx = rem % GX;
        bj[j] = b; gyj[j] = gy; gxj[j] = gx;
        pixbase[j] = ((b * SPI + gy - R0) * SPI + gx) * 40;
    }
    f32x16 acc[JCOLS][2];
    #pragma unroll
    for (int j = 0; j < JCOLS; j++) { acc[j][0] = (f32x16)0.f; acc[j][1] = (f32x16)0.f; }

    uint4 apf[4];
    uint4 bpf[NBT];
    auto loadA = [&](int i0c) {
        #pragma unroll
        for (int r = 0; r < 4; r++)
            if (r < NT)
                apf[r] = *(const uint4*)(wb + (((size_t)(taplist[r] * 512 + o0 + ao)) << 9)
                                          + i0c + ai * 8);
    };
    auto storeA = [&]() {
        #pragma unroll
        for (int r = 0; r < 4; r++)
            if (r < NT)
                *(uint4*)&lds[((r * 4 + ai) * 64 + ao) * 8] = apf[r];
    };
    auto loadB = [&](int i0c) {
        #pragma unroll
        for (int r = 0; r < NBT; r++) {
            int idx = tid + 256 * r;
            if (idx < NBU) {
                int pc = idx >> 2, jj = idx & 3;
                int rr = pc / SPI, cc = pc % SPI;
                int Rc = R0 + rr; if (Rc > ROWMAX) Rc = ROWMAX;
                bpf[r] = *(const uint4*)(Xp + (((size_t)(Rc * SPI + cc)) << 9) + i0c + jj * 8);
            }
        }
    };
    auto storeB = [&]() {
        #pragma unroll
        for (int r = 0; r < NBT; r++) {
            int idx = tid + 256 * r;
            if (idx < NBU) {
                int pc = idx >> 2, jj = idx & 3;
                *(uint4*)&lds[ASZ + pc * 40 + jj * 8] = bpf[r];
            }
        }
    };

    loadA(0); loadB(0);
    for (int c = 0; c < 16; c++) {
        if (c) __syncthreads();
        storeA(); storeB();
        __syncthreads();
        if (c + 1 < 16) { loadA((c + 1) * 32); loadB((c + 1) * 32); }
        for (int tt = 0; tt < NT; ++tt) {
            const int toffB = toffs[tt];
            #pragma unroll
            for (int s = 0; s < 2; s++) {
                const int kl = s * 16 + hf * 8;
                bf16x8 a0 = *(const bf16x8*)&lds[((tt * 4 + s * 2 + hf) * 64 + l31) * 8];
                bf16x8 a1 = *(const bf16x8*)&lds[((tt * 4 + s * 2 + hf) * 64 + 32 + l31) * 8];
                #pragma unroll
                for (int j = 0; j < JCOLS; j++) {
                    bf16x8 bf = *(const bf16x8*)&lds[ASZ + pixbase[j] + toffB + kl];
                    acc[j][0] = __builtin_amdgcn_mfma_f32_32x32x16_bf16(a0, bf, acc[j][0], 0, 0, 0);
                    acc[j][1] = __builtin_amdgcn_mfma_f32_32x32x16_bf16(a1, bf, acc[j][1], 0, 0, 0);
                }
            }
        }
    }
    #pragma unroll
    for (int j = 0; j < JCOLS; j++) {
        if (!validj[j]) continue;
        int b = bj[j];
        int y = 2 * gyj[j] + py, x = 2 * gxj[j] + pxp;
        size_t ubase = ((size_t)(b * SPO + y + 1) * SPO + x + 1) << 9;
        #pragma unroll
        for (int sub = 0; sub < 2; sub++) {
            #pragma unroll
            for (int rq = 0; rq < 4; rq++) {
                int o = o0 + sub * 32 + 4 * hf + 8 * rq;
                float4 d4 = *(const float4*)&dm[b * 512 + o];
                float vv[4];
                #pragma unroll
                for (int ri = 0; ri < 4; ri++)
                    vv[ri] = acc[j][sub][rq * 4 + ri] * (&d4.x)[ri] * CONV_SCALE;
                store4bf(U + ubase + o, vv[0], vv[1], vv[2], vv[3]);
            }
        }
    }
}

// =================== blur 4x4 + noise + bias + lrelu + style ================
template <int SIN>
__global__ void blur_px(const ushort* __restrict__ U, const float* __restrict__ nz,
                        const float* __restrict__ nstr, const float* __restrict__ bias,
                        const float* __restrict__ snext, ushort* __restrict__ X) {
    constexpr int O = SIN - 1, SPI = SIN + 2, SPO = O + 2;
    int gid = blockIdx.x * 256 + threadIdx.x;
    if (gid >= 8 * O * O * 64) return;
    int grp = gid & 63;
    int pxl = gid >> 6;
    int b = pxl / (O * O), r = pxl % (O * O), u = r / O, vcol = r % O;
    const float k1[4] = {0.25f, 0.75f, 0.75f, 0.25f};
    float acc[8];
    #pragma unroll
    for (int k = 0; k < 8; k++) acc[k] = 0.f;
    #pragma unroll
    for (int a = 0; a < 4; a++) {
        int row = b * SPI + u + a;
        #pragma unroll
        for (int c = 0; c < 4; c++) {
            float w = k1[a] * k1[c];
            bf16x8 v = *(const bf16x8*)&U[(((size_t)row * SPI + vcol + c) << 9) + grp * 8];
            #pragma unroll
            for (int k = 0; k < 8; k++) acc[k] += w * bf2f((ushort)v[k]);
        }
    }
    float nsv = nstr[0] * nz[b * O * O + r];
    float4 b0 = *(const float4*)&bias[grp * 8];
    float4 b1 = *(const float4*)&bias[grp * 8 + 4];
    float4 s0 = *(const float4*)&snext[b * 512 + grp * 8];
    float4 s1 = *(const float4*)&snext[b * 512 + grp * 8 + 4];
    union { ushort us[8]; bf16x8 v; } pk;
    #pragma unroll
    for (int k = 0; k < 8; k++) {
        float bk = (k < 4) ? (&b0.x)[k] : (&b1.x)[k - 4];
        float sk = (k < 4) ? (&s0.x)[k] : (&s1.x)[k - 4];
        float v = acc[k] + nsv + bk;
        v = (v > 0.f ? v : 0.2f * v) * SQRT2F;
        pk.us[k] = f2bf(v * sk);
    }
    *(bf16x8*)&X[(((size_t)(b * SPO + u + 1) * SPO + vcol + 1) << 9) + grp * 8] = pk.v;
}

// ======================== skip upsample (up=2, pad 2,1) =====================
template <int H>
__global__ void skipup_kernel(const float* __restrict__ skip, float* __restrict__ out) {
    constexpr int O = 2 * H;
    int idx = blockIdx.x * 256 + threadIdx.x;
    if (idx >= 8 * 3 * O * O) return;
    int px = idx % (O * O);
    int bc = idx / (O * O);
    int u = px / O, v = px % O;
    const float k1[4] = {0.25f, 0.75f, 0.75f, 0.25f};
    const float* src = skip + (size_t)bc * (H * H);
    float acc = 0.f;
    #pragma unroll
    for (int ty = 0; ty < 4; ty++) {
        int r = u + ty - 2;
        if (r < 0 || (r & 1) || (r >> 1) >= H) continue;
        float rsum = 0.f;
        #pragma unroll
        for (int tx = 0; tx < 4; tx++) {
            int cc = v + tx - 2;
            if (cc < 0 || (cc & 1) || (cc >> 1) >= H) continue;
            rsum += k1[tx] * src[(r >> 1) * H + (cc >> 1)];
        }
        acc += k1[ty] * rsum;
    }
    out[(size_t)bc * (O * O) + px] = acc;
}

// ============================ to_rgb (px-major) =============================
__global__ void torgb_px(const ushort* __restrict__ T, int P2,
                         const float* __restrict__ rgbw, const float* __restrict__ srgb,
                         const float* __restrict__ rbias, const float* __restrict__ skipup,
                         float* __restrict__ dst) {
    int b = blockIdx.x;
    int px = blockIdx.y * 4 + (threadIdx.x >> 6);
    int lane = threadIdx.x & 63;
    int c8 = lane * 8;
    bf16x8 v = *(const bf16x8*)&T[(((size_t)b * P2 + px) << 9) + c8];
    float4 sa = *(const float4*)&srgb[b * 512 + c8];
    float4 sb = *(const float4*)&srgb[b * 512 + c8 + 4];
    float xs[8];
    #pragma unroll
    for (int k = 0; k < 8; k++) {
        float sk = (k < 4) ? (&sa.x)[k] : (&sb.x)[k - 4];
        xs[k] = bf2f((ushort)v[k]) * sk;
    }
    float sums[3];
    #pragma unroll
    for (int c = 0; c < 3; c++) {
        float4 w0 = *(const float4*)&rgbw[c * 512 + c8];
        float4 w1 = *(const float4*)&rgbw[c * 512 + c8 + 4];
        float s = 0.f;
        #pragma unroll
        for (int k = 0; k < 8; k++) {
            float wk = (k < 4) ? (&w0.x)[k] : (&w1.x)[k - 4];
            s += xs[k] * wk;
        }
        #pragma unroll
        for (int off = 32; off > 0; off >>= 1) s += __shfl_xor(s, off, 64);
        sums[c] = s;
    }
    if (lane == 0) {
        #pragma unroll
        for (int c = 0; c < 3; c++) {
            float o = sums[c] * RGB_SCALE + rbias[c];
            if (skipup) o += skipup[((size_t)b * 3 + c) * P2 + px];
            dst[((size_t)b * 3 + c) * P2 + px] = o;
        }
    }
}

// ================================ launch ====================================

extern "C" void kernel_launch(void* const* d_in, const int* in_sizes, int n_in,
                              void* d_out, int out_size, void* d_ws, size_t ws_size,
                              hipStream_t stream) {
    const float* z      = (const float*)d_in[0];
    const float* mlp_w  = (const float*)d_in[1];
    const float* mlp_b  = (const float*)d_in[2];
    const float* cinp   = (const float*)d_in[3];
    const float* conv_w = (const float*)d_in[4];
    const float* cmw    = (const float*)d_in[5];
    const float* cmb    = (const float*)d_in[6];
    const float* cbias  = (const float*)d_in[7];
    const float* nstr   = (const float*)d_in[8];
    const float* rgbw   = (const float*)d_in[9];
    const float* rmw    = (const float*)d_in[10];
    const float* rmb    = (const float*)d_in[11];
    const float* rbias  = (const float*)d_in[12];
    float* out = (float*)d_out;
    float* ws = (float*)d_ws;

    // ---- workspace (float-slot offsets) ----
    float* wlatA = ws;                        // 4096
    float* wlatB = ws + 4096;                 // 4096
    float* sconv = ws + 8192;                 // 7*4096
    float* srgb  = ws + 36864;                // 4*4096
    float* dem   = ws + 53248;                // 7*4096
    float* noise = ws + 81920;                // 21632
    float* skipA = ws + 103552;               // 24576
    float* skipB = ws + 128128;               // 24576
    float* skipU = ws + 152704;               // 24576 -> 177280
    float* wsq7  = ws + 177280;               // 7*262144 = 1835008 -> 2012288
    ushort* wbuf7 = (ushort*)(ws + 2012288);  // 7*2359296 us = 8257536 f -> 10269824
    float* Ppart = ws + 10269824;             // 2097152 -> 12366976
    ushort* A1 = (ushort*)(ws + 12366976);    // 5017600 us -> f 14875776
    ushort* A2 = (ushort*)(ws + 14875776);    // 4734976 us -> f 17243264
    ushort* A3 = (ushort*)(ws + 17243264);    // 4194304 us -> f 19340416

    // arena aliases (lifetimes disjoint)
    ushort* X0p = A1;   // 8*6*6*512
    ushort* T0  = A2;   // 8*16*512
    ushort* XU1 = A3;   // 8*6*6*512
    ushort* U1  = A1;   // 8*11*11*512
    ushort* X2  = A2;   // 8*10*10*512
    ushort* T2  = A3;   // 8*64*512
    ushort* XU3 = A1;   // 8*10*10*512
    ushort* U3  = A2;   // 8*19*19*512
    ushort* X4  = A1;   // 8*18*18*512
    ushort* T4  = A2;   // 8*256*512
    ushort* XU5 = A3;   // 8*18*18*512
    ushort* U5  = A1;   // 8*35*35*512
    ushort* X6  = A2;   // 8*34*34*512
    ushort* T6  = A3;   // 8*1024*512

    const size_t LWB = 2359296;  // us per layer in wbuf7

    // weights repack (all layers) + noise (independent of mapping)
    wbconv_all<<<7168, 256, 0, stream>>>(conv_w, wbuf7, wsq7);
    noise_kernel<<<85, 256, 0, stream>>>(noise);

    // mapping network
    pixelnorm_kernel<<<8, 64, 0, stream>>>(z, wlatA);
    float* a = wlatA;
    float* bb = wlatB;
    for (int i = 0; i < 8; i++) {
        dot512_kernel<<<1024, 256, 0, stream>>>(a, mlp_w + (size_t)i * 262144,
                                                mlp_b + i * 512, bb, 4096,
                                                MAP_SCALE, 0.01f, 1);
        float* t = a; a = bb; bb = t;
    }
    dot512_kernel<<<7168, 256, 0, stream>>>(a, cmw, cmb, sconv, 7 * 4096, MOD_SCALE, 1.0f, 0);
    dot512_kernel<<<4096, 256, 0, stream>>>(a, rmw, rmb, srgb, 4 * 4096, MOD_SCALE, 1.0f, 0);
    demod_all<<<7168, 256, 0, stream>>>(wsq7, sconv, dem);
    prep0_kernel<<<72, 256, 0, stream>>>(cinp, sconv, X0p);

    // ---- layer 0 (dense 4x4, old path) ----
    hipMemsetAsync(XU1, 0, (size_t)8 * 36 * 512 * 2, stream);
    conv_dense_s<4, 48, true><<<dim3(8, 1), 256, 0, stream>>>(
        X0p, wbuf7, dem, noise, nstr, cbias, sconv + 4096, T0, XU1);
    torgb_px<<<dim3(8, 4), 256, 0, stream>>>(T0, 16, rgbw, srgb, rbias, nullptr, skipA);

    // ---- layer 1 (up 4->9, all classes) ----
    hipMemsetAsync(U1, 0, (size_t)8 * 121 * 512 * 2, stream);
    conv_up2<4, 128, 48><<<dim3(8, 2, 4), 256, 0, stream>>>(XU1, wbuf7 + LWB, dem + 4096, U1);
    hipMemsetAsync(X2, 0, (size_t)8 * 100 * 512 * 2, stream);
    blur_px<9><<<128, 256, 0, stream>>>(U1, noise + 128, nstr + 1, cbias + 512,
                                        sconv + 2 * 4096, X2);

    // ---- layer 2 (dense 8x8, K-split 4) ----
    conv_dense2<8, 128, 20, 4, false><<<dim3(8, 4, 4), 256, 0, stream>>>(
        X2, wbuf7 + 2 * LWB, nullptr, nullptr, nullptr, nullptr, nullptr,
        nullptr, nullptr, Ppart);
    hipMemsetAsync(XU3, 0, (size_t)8 * 100 * 512 * 2, stream);
    combine_dense<8, 4, true><<<256, 256, 0, stream>>>(
        Ppart, dem + 2 * 4096, noise + 640, nstr + 2, cbias + 2 * 512,
        sconv + 3 * 4096, T2, XU3);
    skipup_kernel<4><<<6, 256, 0, stream>>>(skipA, skipU);
    torgb_px<<<dim3(8, 16), 256, 0, stream>>>(T2, 64, rgbw + 1536, srgb + 4096,
                                              rbias + 3, skipU, skipB);

    // ---- layer 3 (up 8->17, all classes) ----
    hipMemsetAsync(U3, 0, (size_t)8 * 361 * 512 * 2, stream);
    conv_up2<8, 128, 22><<<dim3(8, 6, 4), 256, 0, stream>>>(XU3, wbuf7 + 3 * LWB,
                                                            dem + 3 * 4096, U3);
    hipMemsetAsync(X4, 0, (size_t)8 * 324 * 512 * 2, stream);
    blur_px<17><<<512, 256, 0, stream>>>(U3, noise + 1152, nstr + 3, cbias + 3 * 512,
                                         sconv + 4 * 4096, X4);

    // ---- layer 4 (dense 16x16, K-split 2, WROWS=18: full 16x16 image/block) ----
    conv_dense2<16, 256, 18, 2, false><<<dim3(8, 8, 2), 256, 0, stream>>>(
        X4, wbuf7 + 4 * LWB, nullptr, nullptr, nullptr, nullptr, nullptr,
        nullptr, nullptr, Ppart);
    hipMemsetAsync(XU5, 0, (size_t)8 * 324 * 512 * 2, stream);
    combine_dense<16, 2, true><<<1024, 256, 0, stream>>>(
        Ppart, dem + 4 * 4096, noise + 3200, nstr + 4, cbias + 4 * 512,
        sconv + 5 * 4096, T4, XU5);
    skipup_kernel<8><<<24, 256, 0, stream>>>(skipB, skipU);
    torgb_px<<<dim3(8, 64), 256, 0, stream>>>(T4, 256, rgbw + 2 * 1536, srgb + 2 * 4096,
                                              rbias + 6, skipU, skipA);

    // ---- layer 5 (up 16->33, all classes) ----
    hipMemsetAsync(U5, 0, (size_t)8 * 1225 * 512 * 2, stream);
    conv_up2<16, 256, 20><<<dim3(8, 10, 4), 256, 0, stream>>>(XU5, wbuf7 + 5 * LWB,
                                                              dem + 5 * 4096, U5);
    hipMemsetAsync(X6, 0, (size_t)8 * 1156 * 512 * 2, stream);
    blur_px<33><<<2048, 256, 0, stream>>>(U5, noise + 5248, nstr + 5, cbias + 5 * 512,
                                          sconv + 6 * 4096, X6);

    // ---- layer 6 (dense 32x32, direct epilogue) ----
    conv_dense2<32, 256, 10, 1, false><<<dim3(8, 32, 1), 256, 0, stream>>>(
        X6, wbuf7 + 6 * LWB, dem + 6 * 4096, noise + 13440, nstr + 6, cbias + 6 * 512,
        nullptr, T6, nullptr, nullptr);
    skipup_kernel<16><<<96, 256, 0, stream>>>(skipA, skipU);
    torgb_px<<<dim3(8, 256), 256, 0, stream>>>(T6, 1024, rgbw + 3 * 1536, srgb + 3 * 4096,
                                               rbias + 9, skipU, out);
}